// Round 16
// baseline (358.955 us; speedup 1.0000x reference)
//
#include <hip/hip_runtime.h>
#include <hip/hip_bf16.h>

// Problem constants
#define BB    4
#define TT    1024
#define CC    1024
#define HH    16
#define HSZ   64
#define DFF   4096
#define NTOK  (BB*TT)          // 4096
#define BHN   (BB*HH)          // 64

typedef __attribute__((ext_vector_type(8))) short bf16x8;
typedef __attribute__((ext_vector_type(4))) float f32x4;

#define VMC0  asm volatile("s_waitcnt vmcnt(0)" ::: "memory")
#define LGK0  asm volatile("s_waitcnt lgkmcnt(0)" ::: "memory")
#define BARRIER do { asm volatile("" ::: "memory"); \
                     __builtin_amdgcn_s_barrier();  \
                     asm volatile("" ::: "memory"); } while (0)

// 0.125 * log2(e): folded into Q at the QKV epilogue; v_exp_f32 is exp2.
#define QSCALE 0.18033688f

__device__ __forceinline__ ushort f2b(float v) {
    union { float f; unsigned u; } c; c.f = v;
    unsigned r = c.u + 0x7fffu + ((c.u >> 16) & 1u);   // RNE
    return (ushort)(r >> 16);
}
__device__ __forceinline__ void stv(float* p, float v)  { *p = v; }
__device__ __forceinline__ void stv(ushort* p, float v) { *p = f2b(v); }

__device__ __forceinline__ void gload16(const void* g, void* l) {
    __builtin_amdgcn_global_load_lds(
        (const __attribute__((address_space(1))) void*)g,
        (__attribute__((address_space(3))) void*)l, 16, 0, 0);
}

// ---------------- LayerNorm: f32 in -> bf16 out ------------------------------
__global__ __launch_bounds__(256)
void ln_k(const float* __restrict__ x, const float* __restrict__ g,
          const float* __restrict__ be, ushort* __restrict__ o)
{
    __shared__ float s1[4], s2[4];
    long row = blockIdx.x;
    const float4* xr = (const float4*)(x + row * CC);
    float4 v = xr[threadIdx.x];
    float a = v.x + v.y + v.z + v.w;
    float b = v.x*v.x + v.y*v.y + v.z*v.z + v.w*v.w;
    for (int off = 32; off > 0; off >>= 1) {
        a += __shfl_down(a, off);
        b += __shfl_down(b, off);
    }
    if ((threadIdx.x & 63) == 0) { s1[threadIdx.x >> 6] = a; s2[threadIdx.x >> 6] = b; }
    __syncthreads();
    float sum = s1[0] + s1[1] + s1[2] + s1[3];
    float sq  = s2[0] + s2[1] + s2[2] + s2[3];
    float mu  = sum * (1.0f / CC);
    float var = sq * (1.0f / CC) - mu * mu;
    float inv = rsqrtf(var + 1e-5f);
    float4 gg = ((const float4*)g)[threadIdx.x];
    float4 bb = ((const float4*)be)[threadIdx.x];
    ushort4 r;
    r.x = f2b((v.x - mu) * inv * gg.x + bb.x);
    r.y = f2b((v.y - mu) * inv * gg.y + bb.y);
    r.z = f2b((v.z - mu) * inv * gg.z + bb.z);
    r.w = f2b((v.w - mu) * inv * gg.w + bb.w);
    ((ushort4*)(o + row * CC))[threadIdx.x] = r;
}

// ---------------- All weight conversions (transposed f32->bf16), one launch --
__global__ __launch_bounds__(256)
void cvtall_k(const float* __restrict__ wq, const float* __restrict__ wk,
              const float* __restrict__ wv, const float* __restrict__ wproj,
              const float* __restrict__ w1, const float* __restrict__ w2,
              ushort* __restrict__ wqkvT, ushort* __restrict__ wpT,
              ushort* __restrict__ w1T, ushort* __restrict__ w2T)
{
    __shared__ float t[32][33];
    int idx = blockIdx.x;
    const float* src; ushort* dst; int R, Cc, bx, by;
    if (idx < 3072) {                      // wq/wk/wv: 3 x 16 heads x [1024][64]
        int seg = idx >> 10, rem = idx & 1023;
        int z = rem >> 6, tt2 = rem & 63;
        src = (seg == 0 ? wq : seg == 1 ? wk : wv) + (long)z * 65536;
        dst = wqkvT + (long)seg * (1L << 20) + (long)z * 65536;
        R = 1024; Cc = 64; bx = tt2 & 1; by = tt2 >> 1;
    } else if (idx < 4096) {               // w_proj [1024][1024]
        int tt2 = idx - 3072;
        src = wproj; dst = wpT; R = 1024; Cc = 1024; bx = tt2 & 31; by = tt2 >> 5;
    } else if (idx < 8192) {               // w1 [1024][4096]
        int tt2 = idx - 4096;
        src = w1; dst = w1T; R = 1024; Cc = 4096; bx = tt2 & 127; by = tt2 >> 7;
    } else {                               // w2 [4096][1024]
        int tt2 = idx - 8192;
        src = w2; dst = w2T; R = 4096; Cc = 1024; bx = tt2 & 31; by = tt2 >> 5;
    }
    int r0 = by * 32, c0 = bx * 32;
    int tx = threadIdx.x & 31, ty = threadIdx.x >> 5;
#pragma unroll
    for (int i = 0; i < 4; i++)
        t[ty + 8*i][tx] = src[(long)(r0 + ty + 8*i) * Cc + c0 + tx];
    __syncthreads();
#pragma unroll
    for (int i = 0; i < 4; i++)
        dst[(long)(c0 + ty + 8*i) * R + r0 + tx] = f2b(t[tx][ty + 8*i]);
}

// ---------------- bf16 MFMA GEMM (R6/R8 structure: single buffer) ------------
enum { OL_PLAIN = 0, OL_QKV3 = 1 };
constexpr int EBIAS = 1, ERELU = 2, ERES = 4, ESCALE = 8;

template<int BM, int BN, int WM, int WN, int OL, int EPI, typename OutT>
__global__ __launch_bounds__(256)
void mgemm_k(const ushort* __restrict__ A, const ushort* __restrict__ Bt,
             const float* __restrict__ bias, const float* __restrict__ res,
             OutT* __restrict__ C, int M, int N, int K,
             long sA, long sB, long sC, float scale)
{
    constexpr int BK = 64;
    constexpr int FM = BM / WM / 16, FN = BN / WN / 16;
    __shared__ ushort As[BM * BK];
    __shared__ ushort Bs[BN * BK];
    const int tid = threadIdx.x;
    const int w = tid >> 6, l = tid & 63;
    const int wr = w / WN, wc = w % WN;
    const int l15 = l & 15, l4 = l >> 4;
    const int bh = blockIdx.z;
    const ushort* Ap = A  + (long)bh * sA + (long)(blockIdx.y * BM) * K;
    const ushort* Bp = Bt + (long)bh * sB + (long)(blockIdx.x * BN) * K;

    f32x4 acc[FM][FN];
#pragma unroll
    for (int m = 0; m < FM; m++)
#pragma unroll
        for (int n = 0; n < FN; n++) acc[m][n] = (f32x4){0.f, 0.f, 0.f, 0.f};

    const int arow = tid >> 3;
    const int achk = tid & 7;

    for (int k0 = 0; k0 < K; k0 += BK) {
#pragma unroll
        for (int i = 0; i < BM / 32; i++)
            gload16(Ap + (long)(i*32 + arow) * K + k0 + achk*8,
                    &As[(i*32 + w*8) * BK]);
#pragma unroll
        for (int i = 0; i < BN / 32; i++)
            gload16(Bp + (long)(i*32 + arow) * K + k0 + achk*8,
                    &Bs[(i*32 + w*8) * BK]);
        __syncthreads();
#pragma unroll
        for (int kk = 0; kk < 2; kk++) {
            const int ko = kk*32 + l4*8;
            bf16x8 af[FM], bfr[FN];
#pragma unroll
            for (int m = 0; m < FM; m++)
                af[m] = *(const bf16x8*)&As[(wr*(BM/WM) + m*16 + l15) * BK + ko];
#pragma unroll
            for (int n = 0; n < FN; n++)
                bfr[n] = *(const bf16x8*)&Bs[(wc*(BN/WN) + n*16 + l15) * BK + ko];
#pragma unroll
            for (int m = 0; m < FM; m++)
#pragma unroll
                for (int n = 0; n < FN; n++)
                    acc[m][n] = __builtin_amdgcn_mfma_f32_16x16x32_bf16(
                        af[m], bfr[n], acc[m][n], 0, 0, 0);
        }
        __syncthreads();
    }

#pragma unroll
    for (int m = 0; m < FM; m++) {
        int rbase = blockIdx.y*BM + wr*(BM/WM) + m*16 + l4*4;
#pragma unroll
        for (int n = 0; n < FN; n++) {
            int col = blockIdx.x*BN + wc*(BN/WN) + n*16 + l15;
#pragma unroll
            for (int r = 0; r < 4; r++) {
                int row = rbase + r;
                float v = acc[m][n][r];
                if (EPI & ESCALE) v *= scale;
                if (EPI & EBIAS)  v += bias[col];
                if (EPI & ERELU)  v = fmaxf(v, 0.f);
                if (EPI & ERES)   v += res[(long)row * N + col];
                long idx;
                if (OL == OL_PLAIN) {
                    idx = (long)row * N + col;
                } else {
                    // fused QKV: col segment 0=q(pre-scaled),1=k,2=v(transposed)
                    int seg = col >> 10;
                    int cl  = col & 1023;
                    if (seg == 0) v *= QSCALE;
                    long bh_ = ((long)((row >> 10) * HH + (cl >> 6))) * 65536;
                    long off = (seg == 2)
                        ? bh_ + (long)(cl & 63) * 1024 + (row & 1023)
                        : bh_ + (long)(row & 1023) * 64 + (cl & 63);
                    idx = (long)seg * (4L << 20) + off;
                }
                stv(&C[(long)bh * sC + idx], v);
            }
        }
    }
}

// ---------------- Fused attention, QBLK=256, 8 waves -------------------------
// Pass 1 is BARRIER-FREE: each wave owns 32 rows x all 1024 cols, K fragments
// read directly from global (L2-resident 128KB/head); sums -> sredF -> one
// barrier republishes to pass 2's row mapping. Pass 2 = R8/R15 exact (staged
// K/V, Ps round-trip, deferred nt wei stores). Pass-2 tile-0 K/V prefetch is
// issued at kernel top and drains under all of pass 1.
__global__ __launch_bounds__(512, 2)
void fattn_k(const ushort* __restrict__ q_, const ushort* __restrict__ k_,
             const ushort* __restrict__ vt, float* __restrict__ wei,
             ushort* __restrict__ attn)
{
    __shared__ ushort Qs[256*64];           // 32 KB (pass 2 QK A-operand)
    __shared__ ushort Ks[128*64];           // 16 KB
    __shared__ ushort Vs[64*128];           // 16 KB
    __shared__ ushort Ps[256*128];          // 64 KB; also pass1 sredF scratch
    float* sredF = (float*)Ps;              // [256] row sums

    const int tid = threadIdx.x;
    const int w = tid >> 6, l = tid & 63;   // 8 waves
    const int wr = w >> 1, wc = w & 1;      // pass-2 mapping
    const int l15 = l & 15, l4 = l >> 4;
    const int bh = blockIdx.y;
    const int q0 = blockIdx.x * 256;
    const int arow = tid >> 3, achk = tid & 7;   // staging: 64 rows/issue
    const int kchk = achk ^ (arow & 7);          // swizzled source chunk
    const int vrow = tid >> 4;                   // 32 rows/issue, 256B rows
    const int vchk = (tid & 15) ^ (vrow & 15);
    const int sw8  = (l15 & 7) << 3;             // read XOR, 128B rows
    const int sw16 = l15 << 3;                   // read XOR, 256B rows

    const ushort* Qp = q_ + (long)bh * 65536;
    const ushort* Kp = k_ + (long)bh * 65536;
    const ushort* Vp = vt + (long)bh * 65536;

    // kernel-top staging: Q (pass 2) + pass-2 tile 0 K/V — drains under pass 1
#pragma unroll
    for (int i = 0; i < 4; i++)
        gload16(Qp + (long)(q0 + i*64 + arow) * 64 + kchk*8, &Qs[(i*64 + w*8)*64]);
#pragma unroll
    for (int i = 0; i < 2; i++)
        gload16(Kp + (long)(i*64 + arow) * 64 + kchk*8, &Ks[(i*64 + w*8)*64]);
#pragma unroll
    for (int i = 0; i < 2; i++)
        gload16(Vp + (long)(i*32 + vrow) * 1024 + vchk*8, &Vs[(i*32 + w*4)*128]);

    // ---- pass 1 (barrier-free): wave w owns rows q0 + w*32 .. +32 ----
    {
        const int lq = w * 32;
        bf16x8 qf[2][2];
#pragma unroll
        for (int m = 0; m < 2; m++)
#pragma unroll
            for (int kk = 0; kk < 2; kk++)
                qf[m][kk] = *(const bf16x8*)
                    &Qp[(long)(q0 + lq + m*16 + l15)*64 + kk*32 + l4*8];

        float ssum[2][4];
#pragma unroll
        for (int m = 0; m < 2; m++)
#pragma unroll
            for (int r = 0; r < 4; r++) ssum[m][r] = 0.f;

        for (int st = 0; st < 16; ++st) {
            const ushort* Kt = Kp + (long)st * 64 * 64;
            f32x4 sacc[2][4];
#pragma unroll
            for (int m = 0; m < 2; m++)
#pragma unroll
                for (int n = 0; n < 4; n++) sacc[m][n] = (f32x4){0.f,0.f,0.f,0.f};
#pragma unroll
            for (int kk = 0; kk < 2; kk++) {
                bf16x8 bfr[4];
#pragma unroll
                for (int n = 0; n < 4; n++)
                    bfr[n] = *(const bf16x8*)&Kt[(long)(n*16 + l15)*64 + kk*32 + l4*8];
#pragma unroll
                for (int m = 0; m < 2; m++)
#pragma unroll
                    for (int n = 0; n < 4; n++)
                        sacc[m][n] = __builtin_amdgcn_mfma_f32_16x16x32_bf16(
                            qf[m][kk], bfr[n], sacc[m][n], 0, 0, 0);
            }
#pragma unroll
            for (int m = 0; m < 2; m++)
#pragma unroll
                for (int r = 0; r < 4; r++) {
                    float s = 0.f;
#pragma unroll
                    for (int n = 0; n < 4; n++) s += exp2f(sacc[m][n][r]);
                    ssum[m][r] += s;
                }
        }

        // 16-lane butterfly; lane l15==0 publishes its 8 row sums
#pragma unroll
        for (int m = 0; m < 2; m++)
#pragma unroll
            for (int r = 0; r < 4; r++) {
                float s = ssum[m][r];
#pragma unroll
                for (int d = 1; d < 16; d <<= 1) s += __shfl_xor(s, d);
                if (l15 == 0) sredF[lq + m*16 + l4*4 + r] = s;
            }
    }
    LGK0; BARRIER;

    // pass-2 linv (rows wr*64 + m*16 + l4*4 + r)
    float linv[4][4];
#pragma unroll
    for (int m = 0; m < 4; m++)
#pragma unroll
        for (int r = 0; r < 4; r++)
            linv[m][r] = 1.0f / sredF[wr*64 + m*16 + l4*4 + r];

    // ---- pass 2: P + PV (R8/R15 exact, exp2f) ----
    f32x4 oacc[4][2];
#pragma unroll
    for (int m = 0; m < 4; m++)
#pragma unroll
        for (int n = 0; n < 2; n++) oacc[m][n] = (f32x4){0.f,0.f,0.f,0.f};

    for (int st = 0; st < 8; ++st) {
        if (st > 0) {
#pragma unroll
            for (int i = 0; i < 2; i++)
                gload16(Kp + (long)(st*128 + i*64 + arow) * 64 + kchk*8,
                        &Ks[(i*64 + w*8)*64]);
#pragma unroll
            for (int i = 0; i < 2; i++)
                gload16(Vp + (long)(i*32 + vrow) * 1024 + st*128 + vchk*8,
                        &Vs[(i*32 + w*4)*128]);
        }
        VMC0;              // stage done (prev tile's wei stores drained too)
        BARRIER;

        f32x4 sacc[4][4];
#pragma unroll
        for (int m = 0; m < 4; m++)
#pragma unroll
            for (int n = 0; n < 4; n++) sacc[m][n] = (f32x4){0.f,0.f,0.f,0.f};
        __builtin_amdgcn_s_setprio(1);
#pragma unroll
        for (int kk = 0; kk < 2; kk++) {
            const int ko = kk*32 + l4*8;
            bf16x8 af[4], bfr[4];
#pragma unroll
            for (int m = 0; m < 4; m++)
                af[m] = *(const bf16x8*)&Qs[(wr*64 + m*16 + l15)*64 + (ko ^ sw8)];
#pragma unroll
            for (int n = 0; n < 4; n++)
                bfr[n] = *(const bf16x8*)&Ks[(wc*64 + n*16 + l15)*64 + (ko ^ sw8)];
#pragma unroll
            for (int m = 0; m < 4; m++)
#pragma unroll
                for (int n = 0; n < 4; n++)
                    sacc[m][n] = __builtin_amdgcn_mfma_f32_16x16x32_bf16(
                        af[m], bfr[n], sacc[m][n], 0, 0, 0);
        }
        __builtin_amdgcn_s_setprio(0);

        // exp2 + Ps write; keep normalized p in regs for the deferred wei store
        float pv[4][4][4];
#pragma unroll
        for (int m = 0; m < 4; m++)
#pragma unroll
            for (int r = 0; r < 4; r++) {
                int rg = wr*64 + m*16 + l4*4 + r;
                int psw = (rg & 15) << 3;
                float li = linv[m][r];
#pragma unroll
                for (int n = 0; n < 4; n++) {
                    int col = wc*64 + n*16 + l15;
                    float p = exp2f(sacc[m][n][r]) * li;
                    pv[m][n][r] = p;
                    Ps[rg*128 + (col ^ psw)] = f2b(p);
                }
            }
        LGK0; BARRIER;     // Ps visible to all waves (no vmcnt drain)

        // PV: O += P @ V (normalized P)
        __builtin_amdgcn_s_setprio(1);
#pragma unroll
        for (int kc = 0; kc < 4; ++kc) {
            const int ko = kc*32 + l4*8;
            bf16x8 pa[4], vb[2];
#pragma unroll
            for (int m = 0; m < 4; m++)
                pa[m] = *(const bf16x8*)&Ps[(wr*64 + m*16 + l15)*128 + (ko ^ sw16)];
#pragma unroll
            for (int n = 0; n < 2; n++)
                vb[n] = *(const bf16x8*)&Vs[(wc*32 + n*16 + l15)*128 + (ko ^ sw16)];
#pragma unroll
            for (int m = 0; m < 4; m++)
#pragma unroll
                for (int n = 0; n < 2; n++)
                    oacc[m][n] = __builtin_amdgcn_mfma_f32_16x16x32_bf16(
                        pa[m], vb[n], oacc[m][n], 0, 0, 0);
        }
        __builtin_amdgcn_s_setprio(0);

        // deferred wei stores: overlap PV tail + next tile's staging
        float* wrow = wei + (long)bh * (TT*(long)TT) + st*128;
#pragma unroll
        for (int m = 0; m < 4; m++)
#pragma unroll
            for (int r = 0; r < 4; r++) {
                int rg = wr*64 + m*16 + l4*4 + r;
#pragma unroll
                for (int n = 0; n < 4; n++) {
                    int col = wc*64 + n*16 + l15;
                    __builtin_nontemporal_store(pv[m][n][r],
                        &wrow[(long)(q0 + rg) * TT + col]);
                }
            }
        BARRIER;           // Ks/Vs/Ps reusable next tile (stores in flight)
    }

    // epilogue: attn [B,T,C] bf16
#pragma unroll
    for (int m = 0; m < 4; m++)
#pragma unroll
        for (int r = 0; r < 4; r++) {
            int rg = wr*64 + m*16 + l4*4 + r;
            long rowbase = ((long)(bh >> 4) * TT + q0 + rg) * CC + (long)(bh & 15) * HSZ;
#pragma unroll
            for (int n = 0; n < 2; n++)
                attn[rowbase + wc*32 + n*16 + l15] = f2b(oacc[m][n][r]);
        }
}

// ---------------- launch -----------------------------------------------------
extern "C" void kernel_launch(void* const* d_in, const int* in_sizes, int n_in,
                              void* d_out, int out_size, void* d_ws, size_t ws_size,
                              hipStream_t stream)
{
    const float* x      = (const float*)d_in[0];
    const float* wq     = (const float*)d_in[1];
    const float* wk     = (const float*)d_in[2];
    const float* wv     = (const float*)d_in[3];
    const float* w_proj = (const float*)d_in[4];
    const float* b_proj = (const float*)d_in[5];
    const float* w1     = (const float*)d_in[6];
    const float* b1     = (const float*)d_in[7];
    const float* w2     = (const float*)d_in[8];
    const float* b2     = (const float*)d_in[9];
    const float* g1     = (const float*)d_in[10];
    const float* be1    = (const float*)d_in[11];
    const float* g2     = (const float*)d_in[12];
    const float* be2    = (const float*)d_in[13];

    float* out_x = (float*)d_out;                  // [B,T,C]
    float* wei   = out_x + (long)NTOK * CC;        // [B,H,T,T] f32

    const long MEL = 1 << 20;
    ushort* ws16 = (ushort*)d_ws;
    ushort* h    = ws16;                 // [4096,1024] bf16 (LN1 out)
    ushort* q_   = ws16 + 4*MEL;         // [B,H,T,HS]   (k_ = q_+4M, vt = q_+8M)
    ushort* k_   = ws16 + 8*MEL;
    ushort* vt   = ws16 + 12*MEL;        // [B,H,HS,T]
    ushort* attn = ws16 + 16*MEL;        // [4096,1024] bf16
    ushort* h2   = ws16 + 20*MEL;        // [4096,1024] bf16 (LN2 out)
    ushort* a1   = ws16 + 24*MEL;        // [4096,4096] bf16
    ushort* wqkvT= ws16 + 40*MEL;        // [3072,1024] bf16 (q rows 0-1023, k, v)
    ushort* w1T  = ws16 + 44*MEL;        // [4096,1024]
    ushort* wpT  = ws16 + 48*MEL;        // [1024,1024]
    ushort* w2T  = ws16 + 49*MEL;        // [1024,4096]
    float*  x1   = (float*)(ws16 + 54*MEL);  // [4096,1024] f32

    // all weight conversions in one launch (12288 x 32x32 tiles)
    cvtall_k<<<12288, 256, 0, stream>>>(wq, wk, wv, w_proj, w1, w2,
                                        wqkvT, wpT, w1T, w2T);

    // 1. h = LN(x)
    ln_k<<<NTOK, 256, 0, stream>>>(x, g1, be1, h);

    // 2. fused q,k,v projection (N=3072; q pre-scaled by QSCALE)
    mgemm_k<128,128,2,2,OL_QKV3,0,ushort><<<dim3(24,32,1), 256, 0, stream>>>(
        h, wqkvT, nullptr, nullptr, q_, NTOK, 3072, CC, 0,0,0, 0.f);

    // 3-5. fused attention: wei (f32, d_out) + attn (bf16 headcat)
    fattn_k<<<dim3(4, 64), 512, 0, stream>>>(q_, k_, vt, wei, attn);

    // 6. x1 = x + attn @ w_proj + b_proj  (f32) — BN=64: 2 blk/CU
    mgemm_k<128,64,2,2,OL_PLAIN,EBIAS|ERES,float><<<dim3(16,32,1), 256, 0, stream>>>(
        attn, wpT, b_proj, x, x1, NTOK, CC, CC, 0,0,0, 0.f);

    // 7. h2 = LN(x1)
    ln_k<<<NTOK, 256, 0, stream>>>(x1, g2, be2, h2);

    // 8. a1 = relu(h2 @ w1 + b1)  bf16
    mgemm_k<128,128,2,2,OL_PLAIN,EBIAS|ERELU,ushort><<<dim3(32,32,1), 256, 0, stream>>>(
        h2, w1T, b1, nullptr, a1, NTOK, DFF, CC, 0,0,0, 0.f);

    // 9. out = x1 + a1 @ w2 + b2  (f32) — BN=64: 2 blk/CU
    mgemm_k<128,64,2,2,OL_PLAIN,EBIAS|ERES,float><<<dim3(16,32,1), 256, 0, stream>>>(
        a1, w2T, b2, x1, out_x, NTOK, CC, DFF, 0,0,0, 0.f);
}

// Round 17
// 350.268 us; speedup vs baseline: 1.0248x; 1.0248x over previous
//
#include <hip/hip_runtime.h>
#include <hip/hip_bf16.h>

// Problem constants
#define BB    4
#define TT    1024
#define CC    1024
#define HH    16
#define HSZ   64
#define DFF   4096
#define NTOK  (BB*TT)          // 4096
#define BHN   (BB*HH)          // 64

typedef __attribute__((ext_vector_type(8))) short bf16x8;
typedef __attribute__((ext_vector_type(4))) float f32x4;

#define VMC0  asm volatile("s_waitcnt vmcnt(0)" ::: "memory")
#define VMC2  asm volatile("s_waitcnt vmcnt(2)" ::: "memory")
#define LGK0  asm volatile("s_waitcnt lgkmcnt(0)" ::: "memory")
#define BARRIER do { asm volatile("" ::: "memory"); \
                     __builtin_amdgcn_s_barrier();  \
                     asm volatile("" ::: "memory"); } while (0)

__device__ __forceinline__ ushort f2b(float v) {
    union { float f; unsigned u; } c; c.f = v;
    unsigned r = c.u + 0x7fffu + ((c.u >> 16) & 1u);   // RNE
    return (ushort)(r >> 16);
}
__device__ __forceinline__ void stv(float* p, float v)  { *p = v; }
__device__ __forceinline__ void stv(ushort* p, float v) { *p = f2b(v); }

__device__ __forceinline__ void gload16(const void* g, void* l) {
    __builtin_amdgcn_global_load_lds(
        (const __attribute__((address_space(1))) void*)g,
        (__attribute__((address_space(3))) void*)l, 16, 0, 0);
}

// ---------------- LayerNorm: f32 in -> bf16 out ------------------------------
__global__ __launch_bounds__(256)
void ln_k(const float* __restrict__ x, const float* __restrict__ g,
          const float* __restrict__ be, ushort* __restrict__ o)
{
    __shared__ float s1[4], s2[4];
    long row = blockIdx.x;
    const float4* xr = (const float4*)(x + row * CC);
    float4 v = xr[threadIdx.x];
    float a = v.x + v.y + v.z + v.w;
    float b = v.x*v.x + v.y*v.y + v.z*v.z + v.w*v.w;
    for (int off = 32; off > 0; off >>= 1) {
        a += __shfl_down(a, off);
        b += __shfl_down(b, off);
    }
    if ((threadIdx.x & 63) == 0) { s1[threadIdx.x >> 6] = a; s2[threadIdx.x >> 6] = b; }
    __syncthreads();
    float sum = s1[0] + s1[1] + s1[2] + s1[3];
    float sq  = s2[0] + s2[1] + s2[2] + s2[3];
    float mu  = sum * (1.0f / CC);
    float var = sq * (1.0f / CC) - mu * mu;
    float inv = rsqrtf(var + 1e-5f);
    float4 gg = ((const float4*)g)[threadIdx.x];
    float4 bb = ((const float4*)be)[threadIdx.x];
    ushort4 r;
    r.x = f2b((v.x - mu) * inv * gg.x + bb.x);
    r.y = f2b((v.y - mu) * inv * gg.y + bb.y);
    r.z = f2b((v.z - mu) * inv * gg.z + bb.z);
    r.w = f2b((v.w - mu) * inv * gg.w + bb.w);
    ((ushort4*)(o + row * CC))[threadIdx.x] = r;
}

// ---------------- All weight conversions (transposed f32->bf16), one launch --
__global__ __launch_bounds__(256)
void cvtall_k(const float* __restrict__ wq, const float* __restrict__ wk,
              const float* __restrict__ wv, const float* __restrict__ wproj,
              const float* __restrict__ w1, const float* __restrict__ w2,
              ushort* __restrict__ wqkvT, ushort* __restrict__ wpT,
              ushort* __restrict__ w1T, ushort* __restrict__ w2T)
{
    __shared__ float t[32][33];
    int idx = blockIdx.x;
    const float* src; ushort* dst; int R, Cc, bx, by;
    if (idx < 3072) {                      // wq/wk/wv: 3 x 16 heads x [1024][64]
        int seg = idx >> 10, rem = idx & 1023;
        int z = rem >> 6, tt2 = rem & 63;
        src = (seg == 0 ? wq : seg == 1 ? wk : wv) + (long)z * 65536;
        dst = wqkvT + (long)seg * (1L << 20) + (long)z * 65536;
        R = 1024; Cc = 64; bx = tt2 & 1; by = tt2 >> 1;
    } else if (idx < 4096) {               // w_proj [1024][1024]
        int tt2 = idx - 3072;
        src = wproj; dst = wpT; R = 1024; Cc = 1024; bx = tt2 & 31; by = tt2 >> 5;
    } else if (idx < 8192) {               // w1 [1024][4096]
        int tt2 = idx - 4096;
        src = w1; dst = w1T; R = 1024; Cc = 4096; bx = tt2 & 127; by = tt2 >> 7;
    } else {                               // w2 [4096][1024]
        int tt2 = idx - 8192;
        src = w2; dst = w2T; R = 4096; Cc = 1024; bx = tt2 & 31; by = tt2 >> 5;
    }
    int r0 = by * 32, c0 = bx * 32;
    int tx = threadIdx.x & 31, ty = threadIdx.x >> 5;
#pragma unroll
    for (int i = 0; i < 4; i++)
        t[ty + 8*i][tx] = src[(long)(r0 + ty + 8*i) * Cc + c0 + tx];
    __syncthreads();
#pragma unroll
    for (int i = 0; i < 4; i++)
        dst[(long)(c0 + ty + 8*i) * R + r0 + tx] = f2b(t[tx][ty + 8*i]);
}

// ---------------- bf16 MFMA GEMM (R15 structure: single buffer) --------------
enum { OL_PLAIN = 0, OL_QKV3 = 1 };
constexpr int EBIAS = 1, ERELU = 2, ERES = 4, ESCALE = 8;

template<int BM, int BN, int WM, int WN, int OL, int EPI, typename OutT>
__global__ __launch_bounds__(256)
void mgemm_k(const ushort* __restrict__ A, const ushort* __restrict__ Bt,
             const float* __restrict__ bias, const float* __restrict__ res,
             OutT* __restrict__ C, int M, int N, int K,
             long sA, long sB, long sC, float scale)
{
    constexpr int BK = 64;
    constexpr int FM = BM / WM / 16, FN = BN / WN / 16;
    __shared__ ushort As[BM * BK];
    __shared__ ushort Bs[BN * BK];
    const int tid = threadIdx.x;
    const int w = tid >> 6, l = tid & 63;
    const int wr = w / WN, wc = w % WN;
    const int l15 = l & 15, l4 = l >> 4;
    const int bh = blockIdx.z;
    const ushort* Ap = A  + (long)bh * sA + (long)(blockIdx.y * BM) * K;
    const ushort* Bp = Bt + (long)bh * sB + (long)(blockIdx.x * BN) * K;

    f32x4 acc[FM][FN];
#pragma unroll
    for (int m = 0; m < FM; m++)
#pragma unroll
        for (int n = 0; n < FN; n++) acc[m][n] = (f32x4){0.f, 0.f, 0.f, 0.f};

    const int arow = tid >> 3;
    const int achk = tid & 7;

    for (int k0 = 0; k0 < K; k0 += BK) {
#pragma unroll
        for (int i = 0; i < BM / 32; i++)
            gload16(Ap + (long)(i*32 + arow) * K + k0 + achk*8,
                    &As[(i*32 + w*8) * BK]);
#pragma unroll
        for (int i = 0; i < BN / 32; i++)
            gload16(Bp + (long)(i*32 + arow) * K + k0 + achk*8,
                    &Bs[(i*32 + w*8) * BK]);
        __syncthreads();
#pragma unroll
        for (int kk = 0; kk < 2; kk++) {
            const int ko = kk*32 + l4*8;
            bf16x8 af[FM], bfr[FN];
#pragma unroll
            for (int m = 0; m < FM; m++)
                af[m] = *(const bf16x8*)&As[(wr*(BM/WM) + m*16 + l15) * BK + ko];
#pragma unroll
            for (int n = 0; n < FN; n++)
                bfr[n] = *(const bf16x8*)&Bs[(wc*(BN/WN) + n*16 + l15) * BK + ko];
#pragma unroll
            for (int m = 0; m < FM; m++)
#pragma unroll
                for (int n = 0; n < FN; n++)
                    acc[m][n] = __builtin_amdgcn_mfma_f32_16x16x32_bf16(
                        af[m], bfr[n], acc[m][n], 0, 0, 0);
        }
        __syncthreads();
    }

#pragma unroll
    for (int m = 0; m < FM; m++) {
        int rbase = blockIdx.y*BM + wr*(BM/WM) + m*16 + l4*4;
#pragma unroll
        for (int n = 0; n < FN; n++) {
            int col = blockIdx.x*BN + wc*(BN/WN) + n*16 + l15;
#pragma unroll
            for (int r = 0; r < 4; r++) {
                int row = rbase + r;
                float v = acc[m][n][r];
                if (EPI & ESCALE) v *= scale;
                if (EPI & EBIAS)  v += bias[col];
                if (EPI & ERELU)  v = fmaxf(v, 0.f);
                if (EPI & ERES)   v += res[(long)row * N + col];
                long idx;
                if (OL == OL_PLAIN) {
                    idx = (long)row * N + col;
                } else {
                    // fused QKV: col segment 0=q,1=k,2=v(transposed)
                    int seg = col >> 10;
                    int cl  = col & 1023;
                    long bh_ = ((long)((row >> 10) * HH + (cl >> 6))) * 65536;
                    long off = (seg == 2)
                        ? bh_ + (long)(cl & 63) * 1024 + (row & 1023)
                        : bh_ + (long)(row & 1023) * 64 + (cl & 63);
                    idx = (long)seg * (4L << 20) + off;
                }
                stv(&C[(long)bh * sC + idx], v);
            }
        }
    }
}

// ---------------- 2-phase double-buffered GEMM (T3 minimum recipe) -----------
// One barrier + one vmcnt(0) per K-step; the drain sits AFTER the MFMA so the
// next tile's 6 global_load_lds fly under compute. 128x64 dbuf = 48KB LDS ->
// no occupancy loss at these grid-limited shapes (proj/FF2: 512 blocks=2/CU).
// Race-safety: reads of buf[cur] finish before each wave's MFMA (lgkmcnt),
// MFMA precedes the barrier -> restaging buf[cur] next step is safe; vmcnt(0)
// before the barrier publishes buf[cur^1].
template<int BM, int BN, int WM, int WN, int EPI, typename OutT>
__global__ __launch_bounds__(256)
void mgemm2_k(const ushort* __restrict__ A, const ushort* __restrict__ Bt,
              const float* __restrict__ bias, const float* __restrict__ res,
              OutT* __restrict__ C, int M, int N, int K, float scale)
{
    constexpr int BK = 64;
    constexpr int FM = BM / WM / 16, FN = BN / WN / 16;
    __shared__ ushort As[2][BM * BK];
    __shared__ ushort Bs[2][BN * BK];
    const int tid = threadIdx.x;
    const int w = tid >> 6, l = tid & 63;
    const int wr = w / WN, wc = w % WN;
    const int l15 = l & 15, l4 = l >> 4;
    const ushort* Ap = A  + (long)(blockIdx.y * BM) * K;
    const ushort* Bp = Bt + (long)(blockIdx.x * BN) * K;

    f32x4 acc[FM][FN];
#pragma unroll
    for (int m = 0; m < FM; m++)
#pragma unroll
        for (int n = 0; n < FN; n++) acc[m][n] = (f32x4){0.f, 0.f, 0.f, 0.f};

    const int arow = tid >> 3;
    const int achk = tid & 7;

    auto stage = [&](int buf, int kt) {
        const int k0 = kt * BK;
#pragma unroll
        for (int i = 0; i < BM / 32; i++)
            gload16(Ap + (long)(i*32 + arow) * K + k0 + achk*8,
                    &As[buf][(i*32 + w*8) * BK]);
#pragma unroll
        for (int i = 0; i < BN / 32; i++)
            gload16(Bp + (long)(i*32 + arow) * K + k0 + achk*8,
                    &Bs[buf][(i*32 + w*8) * BK]);
    };

    const int NK = K / BK;
    stage(0, 0);
    VMC0; BARRIER;

    for (int kt = 0; kt < NK; ++kt) {
        const int cur = kt & 1;
        if (kt + 1 < NK)
            stage(cur ^ 1, kt + 1);       // in flight across this MFMA phase
        const ushort* Ac = As[cur];
        const ushort* Bc = Bs[cur];
#pragma unroll
        for (int kk = 0; kk < 2; kk++) {
            const int ko = kk*32 + l4*8;
            bf16x8 af[FM], bfr[FN];
#pragma unroll
            for (int m = 0; m < FM; m++)
                af[m] = *(const bf16x8*)&Ac[(wr*(BM/WM) + m*16 + l15) * BK + ko];
#pragma unroll
            for (int n = 0; n < FN; n++)
                bfr[n] = *(const bf16x8*)&Bc[(wc*(BN/WN) + n*16 + l15) * BK + ko];
#pragma unroll
            for (int m = 0; m < FM; m++)
#pragma unroll
                for (int n = 0; n < FN; n++)
                    acc[m][n] = __builtin_amdgcn_mfma_f32_16x16x32_bf16(
                        af[m], bfr[n], acc[m][n], 0, 0, 0);
        }
        if (kt + 1 < NK) {
            VMC0;          // next tile landed (drain overlapped the MFMAs)
            BARRIER;       // publish buf[cur^1]; all reads of buf[cur] done
        }
    }

    // epilogue (OL_PLAIN)
#pragma unroll
    for (int m = 0; m < FM; m++) {
        int rbase = blockIdx.y*BM + wr*(BM/WM) + m*16 + l4*4;
#pragma unroll
        for (int n = 0; n < FN; n++) {
            int col = blockIdx.x*BN + wc*(BN/WN) + n*16 + l15;
#pragma unroll
            for (int r = 0; r < 4; r++) {
                int row = rbase + r;
                float v = acc[m][n][r];
                if (EPI & ESCALE) v *= scale;
                if (EPI & EBIAS)  v += bias[col];
                if (EPI & ERELU)  v = fmaxf(v, 0.f);
                if (EPI & ERES)   v += res[(long)row * N + col];
                stv(&C[(long)row * N + col], v);
            }
        }
    }
}

// ---------------- Fused attention, QBLK=256, 8 waves (R8/R15 exact) ----------
__global__ __launch_bounds__(512, 2)
void fattn_k(const ushort* __restrict__ q_, const ushort* __restrict__ k_,
             const ushort* __restrict__ vt, float* __restrict__ wei,
             ushort* __restrict__ attn)
{
    __shared__ ushort Qs[256*64];           // 32 KB
    __shared__ ushort Ks[128*64];           // 16 KB
    __shared__ ushort Vs[64*128];           // 16 KB (pass1: K dbuf half)
    __shared__ ushort Ps[256*128];          // 64 KB; pass1-end reduce scratch
    float* sred = (float*)Ps;               // [2][256]

    const int tid = threadIdx.x;
    const int w = tid >> 6, l = tid & 63;   // 8 waves
    const int wr = w >> 1, wc = w & 1;      // wr 0..3, wc 0..1
    const int l15 = l & 15, l4 = l >> 4;
    const int bh = blockIdx.y;
    const int q0 = blockIdx.x * 256;
    const int arow = tid >> 3, achk = tid & 7;   // 64 rows/issue, 128B rows
    const int kchk = achk ^ (arow & 7);          // swizzled source chunk
    const int vrow = tid >> 4;                   // 32 rows/issue, 256B rows
    const int vchk = (tid & 15) ^ (vrow & 15);
    const int sw8  = (l15 & 7) << 3;             // read XOR, 128B rows
    const int sw16 = l15 << 3;                   // read XOR, 256B rows

    const ushort* Qp = q_ + (long)bh * 65536;
    const ushort* Kp = k_ + (long)bh * 65536;
    const ushort* Vp = vt + (long)bh * 65536;

    // stage Q (256 rows, 4 issues) + K tile 0 (2 issues)
#pragma unroll
    for (int i = 0; i < 4; i++)
        gload16(Qp + (long)(q0 + i*64 + arow) * 64 + kchk*8, &Qs[(i*64 + w*8)*64]);
#pragma unroll
    for (int i = 0; i < 2; i++)
        gload16(Kp + (long)(i*64 + arow) * 64 + kchk*8, &Ks[(i*64 + w*8)*64]);

    float ssum[4][4];
#pragma unroll
    for (int m = 0; m < 4; m++)
#pragma unroll
        for (int r = 0; r < 4; r++) ssum[m][r] = 0.f;

    // ---- pass 1: row sums of exp(S); K double-buffered (Ks <-> Vs) ----
    for (int st = 0; st < 8; ++st) {
        const ushort* cur = (st & 1) ? Vs : Ks;
        ushort*       nxt = (st & 1) ? Ks : Vs;
        if (st < 7) {
#pragma unroll
            for (int i = 0; i < 2; i++)
                gload16(Kp + (long)((st+1)*128 + i*64 + arow) * 64 + kchk*8,
                        &nxt[(i*64 + w*8)*64]);
            VMC2;          // current tile's loads done; next-tile 2 in flight
        } else {
            VMC0;
        }
        BARRIER;

        f32x4 sacc[4][4];
#pragma unroll
        for (int m = 0; m < 4; m++)
#pragma unroll
            for (int n = 0; n < 4; n++) sacc[m][n] = (f32x4){0.f,0.f,0.f,0.f};
        __builtin_amdgcn_s_setprio(1);
#pragma unroll
        for (int kk = 0; kk < 2; kk++) {
            const int ko = kk*32 + l4*8;
            bf16x8 af[4], bfr[4];
#pragma unroll
            for (int m = 0; m < 4; m++)
                af[m] = *(const bf16x8*)&Qs[(wr*64 + m*16 + l15)*64 + (ko ^ sw8)];
#pragma unroll
            for (int n = 0; n < 4; n++)
                bfr[n] = *(const bf16x8*)&cur[(wc*64 + n*16 + l15)*64 + (ko ^ sw8)];
#pragma unroll
            for (int m = 0; m < 4; m++)
#pragma unroll
                for (int n = 0; n < 4; n++)
                    sacc[m][n] = __builtin_amdgcn_mfma_f32_16x16x32_bf16(
                        af[m], bfr[n], sacc[m][n], 0, 0, 0);
        }
        __builtin_amdgcn_s_setprio(0);
#pragma unroll
        for (int m = 0; m < 4; m++)
#pragma unroll
            for (int r = 0; r < 4; r++) {
                float s = 0.f;
#pragma unroll
                for (int n = 0; n < 4; n++) s += __expf(sacc[m][n][r] * 0.125f);
                ssum[m][r] += s;
            }
        BARRIER;           // cur consumed by all waves before restage
    }

    // prefetch pass-2 tile 0 (K0 -> Ks, V0 -> Vs) under the reduction
#pragma unroll
    for (int i = 0; i < 2; i++)
        gload16(Kp + (long)(i*64 + arow) * 64 + kchk*8, &Ks[(i*64 + w*8)*64]);
#pragma unroll
    for (int i = 0; i < 2; i++)
        gload16(Vp + (long)(i*32 + vrow) * 1024 + vchk*8, &Vs[(i*32 + w*4)*128]);

    // final reduce: 16 lanes, then across wc via LDS (sred lives in Ps)
    float linv[4][4];
#pragma unroll
    for (int m = 0; m < 4; m++)
#pragma unroll
        for (int r = 0; r < 4; r++) {
            float s = ssum[m][r];
#pragma unroll
            for (int d = 1; d < 16; d <<= 1) s += __shfl_xor(s, d);
            if (l15 == 0) sred[wc*256 + wr*64 + m*16 + l4*4 + r] = s;
        }
    LGK0; BARRIER;
#pragma unroll
    for (int m = 0; m < 4; m++)
#pragma unroll
        for (int r = 0; r < 4; r++) {
            int rg = wr*64 + m*16 + l4*4 + r;
            linv[m][r] = 1.0f / (sred[rg] + sred[256 + rg]);
        }

    // ---- pass 2: P + PV ----
    f32x4 oacc[4][2];
#pragma unroll
    for (int m = 0; m < 4; m++)
#pragma unroll
        for (int n = 0; n < 2; n++) oacc[m][n] = (f32x4){0.f,0.f,0.f,0.f};

    for (int st = 0; st < 8; ++st) {
        if (st > 0) {
#pragma unroll
            for (int i = 0; i < 2; i++)
                gload16(Kp + (long)(st*128 + i*64 + arow) * 64 + kchk*8,
                        &Ks[(i*64 + w*8)*64]);
#pragma unroll
            for (int i = 0; i < 2; i++)
                gload16(Vp + (long)(i*32 + vrow) * 1024 + st*128 + vchk*8,
                        &Vs[(i*32 + w*4)*128]);
        }
        VMC0;              // stage done (prev tile's wei stores drained too)
        BARRIER;

        f32x4 sacc[4][4];
#pragma unroll
        for (int m = 0; m < 4; m++)
#pragma unroll
            for (int n = 0; n < 4; n++) sacc[m][n] = (f32x4){0.f,0.f,0.f,0.f};
        __builtin_amdgcn_s_setprio(1);
#pragma unroll
        for (int kk = 0; kk < 2; kk++) {
            const int ko = kk*32 + l4*8;
            bf16x8 af[4], bfr[4];
#pragma unroll
            for (int m = 0; m < 4; m++)
                af[m] = *(const bf16x8*)&Qs[(wr*64 + m*16 + l15)*64 + (ko ^ sw8)];
#pragma unroll
            for (int n = 0; n < 4; n++)
                bfr[n] = *(const bf16x8*)&Ks[(wc*64 + n*16 + l15)*64 + (ko ^ sw8)];
#pragma unroll
            for (int m = 0; m < 4; m++)
#pragma unroll
                for (int n = 0; n < 4; n++)
                    sacc[m][n] = __builtin_amdgcn_mfma_f32_16x16x32_bf16(
                        af[m], bfr[n], sacc[m][n], 0, 0, 0);
        }
        __builtin_amdgcn_s_setprio(0);

        // exp + Ps write; keep normalized p in regs for the deferred wei store
        float pv[4][4][4];
#pragma unroll
        for (int m = 0; m < 4; m++)
#pragma unroll
            for (int r = 0; r < 4; r++) {
                int rg = wr*64 + m*16 + l4*4 + r;
                int psw = (rg & 15) << 3;
                float li = linv[m][r];
#pragma unroll
                for (int n = 0; n < 4; n++) {
                    int col = wc*64 + n*16 + l15;
                    float p = __expf(sacc[m][n][r] * 0.125f) * li;
                    pv[m][n][r] = p;
                    Ps[rg*128 + (col ^ psw)] = f2b(p);
                }
            }
        LGK0; BARRIER;     // Ps visible to all waves (no vmcnt drain)

        // PV: O += P @ V (normalized P)
        __builtin_amdgcn_s_setprio(1);
#pragma unroll
        for (int kc = 0; kc < 4; ++kc) {
            const int ko = kc*32 + l4*8;
            bf16x8 pa[4], vb[2];
#pragma unroll
            for (int m = 0; m < 4; m++)
                pa[m] = *(const bf16x8*)&Ps[(wr*64 + m*16 + l15)*128 + (ko ^ sw16)];
#pragma unroll
            for (int n = 0; n < 2; n++)
                vb[n] = *(const bf16x8*)&Vs[(wc*32 + n*16 + l15)*128 + (ko ^ sw16)];
#pragma unroll
            for (int m = 0; m < 4; m++)
#pragma unroll
                for (int n = 0; n < 2; n++)
                    oacc[m][n] = __builtin_amdgcn_mfma_f32_16x16x32_bf16(
                        pa[m], vb[n], oacc[m][n], 0, 0, 0);
        }
        __builtin_amdgcn_s_setprio(0);

        // deferred wei stores: overlap PV tail + next tile's staging
        float* wrow = wei + (long)bh * (TT*(long)TT) + st*128;
#pragma unroll
        for (int m = 0; m < 4; m++)
#pragma unroll
            for (int r = 0; r < 4; r++) {
                int rg = wr*64 + m*16 + l4*4 + r;
#pragma unroll
                for (int n = 0; n < 4; n++) {
                    int col = wc*64 + n*16 + l15;
                    __builtin_nontemporal_store(pv[m][n][r],
                        &wrow[(long)(q0 + rg) * TT + col]);
                }
            }
        BARRIER;           // Ks/Vs/Ps reusable next tile (stores in flight)
    }

    // epilogue: attn [B,T,C] bf16
#pragma unroll
    for (int m = 0; m < 4; m++)
#pragma unroll
        for (int r = 0; r < 4; r++) {
            int rg = wr*64 + m*16 + l4*4 + r;
            long rowbase = ((long)(bh >> 4) * TT + q0 + rg) * CC + (long)(bh & 15) * HSZ;
#pragma unroll
            for (int n = 0; n < 2; n++)
                attn[rowbase + wc*32 + n*16 + l15] = f2b(oacc[m][n][r]);
        }
}

// ---------------- launch -----------------------------------------------------
extern "C" void kernel_launch(void* const* d_in, const int* in_sizes, int n_in,
                              void* d_out, int out_size, void* d_ws, size_t ws_size,
                              hipStream_t stream)
{
    const float* x      = (const float*)d_in[0];
    const float* wq     = (const float*)d_in[1];
    const float* wk     = (const float*)d_in[2];
    const float* wv     = (const float*)d_in[3];
    const float* w_proj = (const float*)d_in[4];
    const float* b_proj = (const float*)d_in[5];
    const float* w1     = (const float*)d_in[6];
    const float* b1     = (const float*)d_in[7];
    const float* w2     = (const float*)d_in[8];
    const float* b2     = (const float*)d_in[9];
    const float* g1     = (const float*)d_in[10];
    const float* be1    = (const float*)d_in[11];
    const float* g2     = (const float*)d_in[12];
    const float* be2    = (const float*)d_in[13];

    float* out_x = (float*)d_out;                  // [B,T,C]
    float* wei   = out_x + (long)NTOK * CC;        // [B,H,T,T] f32

    const long MEL = 1 << 20;
    ushort* ws16 = (ushort*)d_ws;
    ushort* h    = ws16;                 // [4096,1024] bf16 (LN1 out)
    ushort* q_   = ws16 + 4*MEL;         // [B,H,T,HS]   (k_ = q_+4M, vt = q_+8M)
    ushort* k_   = ws16 + 8*MEL;
    ushort* vt   = ws16 + 12*MEL;        // [B,H,HS,T]
    ushort* attn = ws16 + 16*MEL;        // [4096,1024] bf16
    ushort* h2   = ws16 + 20*MEL;        // [4096,1024] bf16 (LN2 out)
    ushort* a1   = ws16 + 24*MEL;        // [4096,4096] bf16
    ushort* wqkvT= ws16 + 40*MEL;        // [3072,1024] bf16 (q rows 0-1023, k, v)
    ushort* w1T  = ws16 + 44*MEL;        // [4096,1024]
    ushort* wpT  = ws16 + 48*MEL;        // [1024,1024]
    ushort* w2T  = ws16 + 49*MEL;        // [1024,4096]
    float*  x1   = (float*)(ws16 + 54*MEL);  // [4096,1024] f32

    // all weight conversions in one launch (12288 x 32x32 tiles)
    cvtall_k<<<12288, 256, 0, stream>>>(wq, wk, wv, w_proj, w1, w2,
                                        wqkvT, wpT, w1T, w2T);

    // 1. h = LN(x)
    ln_k<<<NTOK, 256, 0, stream>>>(x, g1, be1, h);

    // 2. fused q,k,v projection (N=3072)
    mgemm_k<128,128,2,2,OL_QKV3,0,ushort><<<dim3(24,32,1), 256, 0, stream>>>(
        h, wqkvT, nullptr, nullptr, q_, NTOK, 3072, CC, 0,0,0, 0.f);

    // 3-5. fused attention: wei (f32, d_out) + attn (bf16 headcat)
    fattn_k<<<dim3(4, 64), 512, 0, stream>>>(q_, k_, vt, wei, attn);

    // 6. x1 = x + attn @ w_proj + b_proj  (f32) — 2-phase dbuf, BN=64
    mgemm2_k<128,64,2,2,EBIAS|ERES,float><<<dim3(16,32,1), 256, 0, stream>>>(
        attn, wpT, b_proj, x, x1, NTOK, CC, CC, 0.f);

    // 7. h2 = LN(x1)
    ln_k<<<NTOK, 256, 0, stream>>>(x1, g2, be2, h2);

    // 8. a1 = relu(h2 @ w1 + b1)  bf16 (R15 single-buffer, proven)
    mgemm_k<128,128,2,2,OL_PLAIN,EBIAS|ERELU,ushort><<<dim3(32,32,1), 256, 0, stream>>>(
        h2, w1T, b1, nullptr, a1, NTOK, DFF, CC, 0,0,0, 0.f);

    // 9. out = x1 + a1 @ w2 + b2  (f32) — 2-phase dbuf, BN=64
    mgemm2_k<128,64,2,2,EBIAS|ERES,float><<<dim3(16,32,1), 256, 0, stream>>>(
        a1, w2T, b2, x1, out_x, NTOK, CC, DFF, 0.f);
}

// Round 18
// 349.210 us; speedup vs baseline: 1.0279x; 1.0030x over previous
//
#include <hip/hip_runtime.h>
#include <hip/hip_bf16.h>

// Problem constants
#define BB    4
#define TT    1024
#define CC    1024
#define HH    16
#define HSZ   64
#define DFF   4096
#define NTOK  (BB*TT)          // 4096
#define BHN   (BB*HH)          // 64

typedef __attribute__((ext_vector_type(8))) short bf16x8;
typedef __attribute__((ext_vector_type(4))) float f32x4;

#define VMC0  asm volatile("s_waitcnt vmcnt(0)" ::: "memory")
#define VMC2  asm volatile("s_waitcnt vmcnt(2)" ::: "memory")
#define LGK0  asm volatile("s_waitcnt lgkmcnt(0)" ::: "memory")
#define BARRIER do { asm volatile("" ::: "memory"); \
                     __builtin_amdgcn_s_barrier();  \
                     asm volatile("" ::: "memory"); } while (0)

// 0.125 * log2(e): folded into Q at the QKV epilogue; v_exp_f32 is exp2.
#define QSCALE 0.18033688f

__device__ __forceinline__ ushort f2b(float v) {
    union { float f; unsigned u; } c; c.f = v;
    unsigned r = c.u + 0x7fffu + ((c.u >> 16) & 1u);   // RNE
    return (ushort)(r >> 16);
}
__device__ __forceinline__ void stv(float* p, float v)  { *p = v; }
__device__ __forceinline__ void stv(ushort* p, float v) { *p = f2b(v); }

__device__ __forceinline__ void gload16(const void* g, void* l) {
    __builtin_amdgcn_global_load_lds(
        (const __attribute__((address_space(1))) void*)g,
        (__attribute__((address_space(3))) void*)l, 16, 0, 0);
}

// ---------------- LayerNorm: f32 in -> bf16 out ------------------------------
__global__ __launch_bounds__(256)
void ln_k(const float* __restrict__ x, const float* __restrict__ g,
          const float* __restrict__ be, ushort* __restrict__ o)
{
    __shared__ float s1[4], s2[4];
    long row = blockIdx.x;
    const float4* xr = (const float4*)(x + row * CC);
    float4 v = xr[threadIdx.x];
    float a = v.x + v.y + v.z + v.w;
    float b = v.x*v.x + v.y*v.y + v.z*v.z + v.w*v.w;
    for (int off = 32; off > 0; off >>= 1) {
        a += __shfl_down(a, off);
        b += __shfl_down(b, off);
    }
    if ((threadIdx.x & 63) == 0) { s1[threadIdx.x >> 6] = a; s2[threadIdx.x >> 6] = b; }
    __syncthreads();
    float sum = s1[0] + s1[1] + s1[2] + s1[3];
    float sq  = s2[0] + s2[1] + s2[2] + s2[3];
    float mu  = sum * (1.0f / CC);
    float var = sq * (1.0f / CC) - mu * mu;
    float inv = rsqrtf(var + 1e-5f);
    float4 gg = ((const float4*)g)[threadIdx.x];
    float4 bb = ((const float4*)be)[threadIdx.x];
    ushort4 r;
    r.x = f2b((v.x - mu) * inv * gg.x + bb.x);
    r.y = f2b((v.y - mu) * inv * gg.y + bb.y);
    r.z = f2b((v.z - mu) * inv * gg.z + bb.z);
    r.w = f2b((v.w - mu) * inv * gg.w + bb.w);
    ((ushort4*)(o + row * CC))[threadIdx.x] = r;
}

// ---------------- All weight conversions (transposed f32->bf16), one launch --
__global__ __launch_bounds__(256)
void cvtall_k(const float* __restrict__ wq, const float* __restrict__ wk,
              const float* __restrict__ wv, const float* __restrict__ wproj,
              const float* __restrict__ w1, const float* __restrict__ w2,
              ushort* __restrict__ wqkvT, ushort* __restrict__ wpT,
              ushort* __restrict__ w1T, ushort* __restrict__ w2T)
{
    __shared__ float t[32][33];
    int idx = blockIdx.x;
    const float* src; ushort* dst; int R, Cc, bx, by;
    if (idx < 3072) {                      // wq/wk/wv: 3 x 16 heads x [1024][64]
        int seg = idx >> 10, rem = idx & 1023;
        int z = rem >> 6, tt2 = rem & 63;
        src = (seg == 0 ? wq : seg == 1 ? wk : wv) + (long)z * 65536;
        dst = wqkvT + (long)seg * (1L << 20) + (long)z * 65536;
        R = 1024; Cc = 64; bx = tt2 & 1; by = tt2 >> 1;
    } else if (idx < 4096) {               // w_proj [1024][1024]
        int tt2 = idx - 3072;
        src = wproj; dst = wpT; R = 1024; Cc = 1024; bx = tt2 & 31; by = tt2 >> 5;
    } else if (idx < 8192) {               // w1 [1024][4096]
        int tt2 = idx - 4096;
        src = w1; dst = w1T; R = 1024; Cc = 4096; bx = tt2 & 127; by = tt2 >> 7;
    } else {                               // w2 [4096][1024]
        int tt2 = idx - 8192;
        src = w2; dst = w2T; R = 4096; Cc = 1024; bx = tt2 & 31; by = tt2 >> 5;
    }
    int r0 = by * 32, c0 = bx * 32;
    int tx = threadIdx.x & 31, ty = threadIdx.x >> 5;
#pragma unroll
    for (int i = 0; i < 4; i++)
        t[ty + 8*i][tx] = src[(long)(r0 + ty + 8*i) * Cc + c0 + tx];
    __syncthreads();
#pragma unroll
    for (int i = 0; i < 4; i++)
        dst[(long)(c0 + ty + 8*i) * R + r0 + tx] = f2b(t[tx][ty + 8*i]);
}

// ---------------- bf16 MFMA GEMM (R15 structure: single buffer) --------------
enum { OL_PLAIN = 0, OL_QKV3 = 1 };
constexpr int EBIAS = 1, ERELU = 2, ERES = 4, ESCALE = 8;

template<int BM, int BN, int WM, int WN, int OL, int EPI, typename OutT>
__global__ __launch_bounds__(256)
void mgemm_k(const ushort* __restrict__ A, const ushort* __restrict__ Bt,
             const float* __restrict__ bias, const float* __restrict__ res,
             OutT* __restrict__ C, int M, int N, int K,
             long sA, long sB, long sC, float scale)
{
    constexpr int BK = 64;
    constexpr int FM = BM / WM / 16, FN = BN / WN / 16;
    __shared__ ushort As[BM * BK];
    __shared__ ushort Bs[BN * BK];
    const int tid = threadIdx.x;
    const int w = tid >> 6, l = tid & 63;
    const int wr = w / WN, wc = w % WN;
    const int l15 = l & 15, l4 = l >> 4;
    const int bh = blockIdx.z;
    const ushort* Ap = A  + (long)bh * sA + (long)(blockIdx.y * BM) * K;
    const ushort* Bp = Bt + (long)bh * sB + (long)(blockIdx.x * BN) * K;

    f32x4 acc[FM][FN];
#pragma unroll
    for (int m = 0; m < FM; m++)
#pragma unroll
        for (int n = 0; n < FN; n++) acc[m][n] = (f32x4){0.f, 0.f, 0.f, 0.f};

    const int arow = tid >> 3;
    const int achk = tid & 7;

    for (int k0 = 0; k0 < K; k0 += BK) {
#pragma unroll
        for (int i = 0; i < BM / 32; i++)
            gload16(Ap + (long)(i*32 + arow) * K + k0 + achk*8,
                    &As[(i*32 + w*8) * BK]);
#pragma unroll
        for (int i = 0; i < BN / 32; i++)
            gload16(Bp + (long)(i*32 + arow) * K + k0 + achk*8,
                    &Bs[(i*32 + w*8) * BK]);
        __syncthreads();
#pragma unroll
        for (int kk = 0; kk < 2; kk++) {
            const int ko = kk*32 + l4*8;
            bf16x8 af[FM], bfr[FN];
#pragma unroll
            for (int m = 0; m < FM; m++)
                af[m] = *(const bf16x8*)&As[(wr*(BM/WM) + m*16 + l15) * BK + ko];
#pragma unroll
            for (int n = 0; n < FN; n++)
                bfr[n] = *(const bf16x8*)&Bs[(wc*(BN/WN) + n*16 + l15) * BK + ko];
#pragma unroll
            for (int m = 0; m < FM; m++)
#pragma unroll
                for (int n = 0; n < FN; n++)
                    acc[m][n] = __builtin_amdgcn_mfma_f32_16x16x32_bf16(
                        af[m], bfr[n], acc[m][n], 0, 0, 0);
        }
        __syncthreads();
    }

#pragma unroll
    for (int m = 0; m < FM; m++) {
        int rbase = blockIdx.y*BM + wr*(BM/WM) + m*16 + l4*4;
#pragma unroll
        for (int n = 0; n < FN; n++) {
            int col = blockIdx.x*BN + wc*(BN/WN) + n*16 + l15;
#pragma unroll
            for (int r = 0; r < 4; r++) {
                int row = rbase + r;
                float v = acc[m][n][r];
                if (EPI & ESCALE) v *= scale;
                if (EPI & EBIAS)  v += bias[col];
                if (EPI & ERELU)  v = fmaxf(v, 0.f);
                if (EPI & ERES)   v += res[(long)row * N + col];
                long idx;
                if (OL == OL_PLAIN) {
                    idx = (long)row * N + col;
                } else {
                    // fused QKV: col segment 0=q(pre-scaled),1=k,2=v(transposed)
                    int seg = col >> 10;
                    int cl  = col & 1023;
                    if (seg == 0) v *= QSCALE;
                    long bh_ = ((long)((row >> 10) * HH + (cl >> 6))) * 65536;
                    long off = (seg == 2)
                        ? bh_ + (long)(cl & 63) * 1024 + (row & 1023)
                        : bh_ + (long)(row & 1023) * 64 + (cl & 63);
                    idx = (long)seg * (4L << 20) + off;
                }
                stv(&C[(long)bh * sC + idx], v);
            }
        }
    }
}

// ---------------- Fused attention, QBLK=256, 8 waves (R8/R15 structure) ------
// Identical sync/store structure to the 342us R15 run; only change: Q carries
// QSCALE (0.125*log2e) so exp is a bare exp2f (v_exp_f32 IS exp2 -> one v_mul
// per element deleted in both passes).
__global__ __launch_bounds__(512, 2)
void fattn_k(const ushort* __restrict__ q_, const ushort* __restrict__ k_,
             const ushort* __restrict__ vt, float* __restrict__ wei,
             ushort* __restrict__ attn)
{
    __shared__ ushort Qs[256*64];           // 32 KB
    __shared__ ushort Ks[128*64];           // 16 KB
    __shared__ ushort Vs[64*128];           // 16 KB (pass1: K dbuf half)
    __shared__ ushort Ps[256*128];          // 64 KB; pass1-end reduce scratch
    float* sred = (float*)Ps;               // [2][256]

    const int tid = threadIdx.x;
    const int w = tid >> 6, l = tid & 63;   // 8 waves
    const int wr = w >> 1, wc = w & 1;      // wr 0..3, wc 0..1
    const int l15 = l & 15, l4 = l >> 4;
    const int bh = blockIdx.y;
    const int q0 = blockIdx.x * 256;
    const int arow = tid >> 3, achk = tid & 7;   // 64 rows/issue, 128B rows
    const int kchk = achk ^ (arow & 7);          // swizzled source chunk
    const int vrow = tid >> 4;                   // 32 rows/issue, 256B rows
    const int vchk = (tid & 15) ^ (vrow & 15);
    const int sw8  = (l15 & 7) << 3;             // read XOR, 128B rows
    const int sw16 = l15 << 3;                   // read XOR, 256B rows

    const ushort* Qp = q_ + (long)bh * 65536;
    const ushort* Kp = k_ + (long)bh * 65536;
    const ushort* Vp = vt + (long)bh * 65536;

    // stage Q (256 rows, 4 issues) + K tile 0 (2 issues)
#pragma unroll
    for (int i = 0; i < 4; i++)
        gload16(Qp + (long)(q0 + i*64 + arow) * 64 + kchk*8, &Qs[(i*64 + w*8)*64]);
#pragma unroll
    for (int i = 0; i < 2; i++)
        gload16(Kp + (long)(i*64 + arow) * 64 + kchk*8, &Ks[(i*64 + w*8)*64]);

    float ssum[4][4];
#pragma unroll
    for (int m = 0; m < 4; m++)
#pragma unroll
        for (int r = 0; r < 4; r++) ssum[m][r] = 0.f;

    // ---- pass 1: row sums of exp2(S); K double-buffered (Ks <-> Vs) ----
    for (int st = 0; st < 8; ++st) {
        const ushort* cur = (st & 1) ? Vs : Ks;
        ushort*       nxt = (st & 1) ? Ks : Vs;
        if (st < 7) {
#pragma unroll
            for (int i = 0; i < 2; i++)
                gload16(Kp + (long)((st+1)*128 + i*64 + arow) * 64 + kchk*8,
                        &nxt[(i*64 + w*8)*64]);
            VMC2;          // current tile's loads done; next-tile 2 in flight
        } else {
            VMC0;
        }
        BARRIER;

        f32x4 sacc[4][4];
#pragma unroll
        for (int m = 0; m < 4; m++)
#pragma unroll
            for (int n = 0; n < 4; n++) sacc[m][n] = (f32x4){0.f,0.f,0.f,0.f};
        __builtin_amdgcn_s_setprio(1);
#pragma unroll
        for (int kk = 0; kk < 2; kk++) {
            const int ko = kk*32 + l4*8;
            bf16x8 af[4], bfr[4];
#pragma unroll
            for (int m = 0; m < 4; m++)
                af[m] = *(const bf16x8*)&Qs[(wr*64 + m*16 + l15)*64 + (ko ^ sw8)];
#pragma unroll
            for (int n = 0; n < 4; n++)
                bfr[n] = *(const bf16x8*)&cur[(wc*64 + n*16 + l15)*64 + (ko ^ sw8)];
#pragma unroll
            for (int m = 0; m < 4; m++)
#pragma unroll
                for (int n = 0; n < 4; n++)
                    sacc[m][n] = __builtin_amdgcn_mfma_f32_16x16x32_bf16(
                        af[m], bfr[n], sacc[m][n], 0, 0, 0);
        }
        __builtin_amdgcn_s_setprio(0);
#pragma unroll
        for (int m = 0; m < 4; m++)
#pragma unroll
            for (int r = 0; r < 4; r++) {
                float s = 0.f;
#pragma unroll
                for (int n = 0; n < 4; n++) s += exp2f(sacc[m][n][r]);
                ssum[m][r] += s;
            }
        BARRIER;           // cur consumed by all waves before restage
    }

    // prefetch pass-2 tile 0 (K0 -> Ks, V0 -> Vs) under the reduction
#pragma unroll
    for (int i = 0; i < 2; i++)
        gload16(Kp + (long)(i*64 + arow) * 64 + kchk*8, &Ks[(i*64 + w*8)*64]);
#pragma unroll
    for (int i = 0; i < 2; i++)
        gload16(Vp + (long)(i*32 + vrow) * 1024 + vchk*8, &Vs[(i*32 + w*4)*128]);

    // final reduce: 16 lanes, then across wc via LDS (sred lives in Ps)
    float linv[4][4];
#pragma unroll
    for (int m = 0; m < 4; m++)
#pragma unroll
        for (int r = 0; r < 4; r++) {
            float s = ssum[m][r];
#pragma unroll
            for (int d = 1; d < 16; d <<= 1) s += __shfl_xor(s, d);
            if (l15 == 0) sred[wc*256 + wr*64 + m*16 + l4*4 + r] = s;
        }
    LGK0; BARRIER;
#pragma unroll
    for (int m = 0; m < 4; m++)
#pragma unroll
        for (int r = 0; r < 4; r++) {
            int rg = wr*64 + m*16 + l4*4 + r;
            linv[m][r] = 1.0f / (sred[rg] + sred[256 + rg]);
        }

    // ---- pass 2: P + PV ----
    f32x4 oacc[4][2];
#pragma unroll
    for (int m = 0; m < 4; m++)
#pragma unroll
        for (int n = 0; n < 2; n++) oacc[m][n] = (f32x4){0.f,0.f,0.f,0.f};

    for (int st = 0; st < 8; ++st) {
        if (st > 0) {
#pragma unroll
            for (int i = 0; i < 2; i++)
                gload16(Kp + (long)(st*128 + i*64 + arow) * 64 + kchk*8,
                        &Ks[(i*64 + w*8)*64]);
#pragma unroll
            for (int i = 0; i < 2; i++)
                gload16(Vp + (long)(i*32 + vrow) * 1024 + st*128 + vchk*8,
                        &Vs[(i*32 + w*4)*128]);
        }
        VMC0;              // stage done (prev tile's wei stores drained too)
        BARRIER;

        f32x4 sacc[4][4];
#pragma unroll
        for (int m = 0; m < 4; m++)
#pragma unroll
            for (int n = 0; n < 4; n++) sacc[m][n] = (f32x4){0.f,0.f,0.f,0.f};
        __builtin_amdgcn_s_setprio(1);
#pragma unroll
        for (int kk = 0; kk < 2; kk++) {
            const int ko = kk*32 + l4*8;
            bf16x8 af[4], bfr[4];
#pragma unroll
            for (int m = 0; m < 4; m++)
                af[m] = *(const bf16x8*)&Qs[(wr*64 + m*16 + l15)*64 + (ko ^ sw8)];
#pragma unroll
            for (int n = 0; n < 4; n++)
                bfr[n] = *(const bf16x8*)&Ks[(wc*64 + n*16 + l15)*64 + (ko ^ sw8)];
#pragma unroll
            for (int m = 0; m < 4; m++)
#pragma unroll
                for (int n = 0; n < 4; n++)
                    sacc[m][n] = __builtin_amdgcn_mfma_f32_16x16x32_bf16(
                        af[m], bfr[n], sacc[m][n], 0, 0, 0);
        }
        __builtin_amdgcn_s_setprio(0);

        // exp2 + Ps write; keep normalized p in regs for the deferred wei store
        float pv[4][4][4];
#pragma unroll
        for (int m = 0; m < 4; m++)
#pragma unroll
            for (int r = 0; r < 4; r++) {
                int rg = wr*64 + m*16 + l4*4 + r;
                int psw = (rg & 15) << 3;
                float li = linv[m][r];
#pragma unroll
                for (int n = 0; n < 4; n++) {
                    int col = wc*64 + n*16 + l15;
                    float p = exp2f(sacc[m][n][r]) * li;
                    pv[m][n][r] = p;
                    Ps[rg*128 + (col ^ psw)] = f2b(p);
                }
            }
        LGK0; BARRIER;     // Ps visible to all waves (no vmcnt drain)

        // PV: O += P @ V (normalized P)
        __builtin_amdgcn_s_setprio(1);
#pragma unroll
        for (int kc = 0; kc < 4; ++kc) {
            const int ko = kc*32 + l4*8;
            bf16x8 pa[4], vb[2];
#pragma unroll
            for (int m = 0; m < 4; m++)
                pa[m] = *(const bf16x8*)&Ps[(wr*64 + m*16 + l15)*128 + (ko ^ sw16)];
#pragma unroll
            for (int n = 0; n < 2; n++)
                vb[n] = *(const bf16x8*)&Vs[(wc*32 + n*16 + l15)*128 + (ko ^ sw16)];
#pragma unroll
            for (int m = 0; m < 4; m++)
#pragma unroll
                for (int n = 0; n < 2; n++)
                    oacc[m][n] = __builtin_amdgcn_mfma_f32_16x16x32_bf16(
                        pa[m], vb[n], oacc[m][n], 0, 0, 0);
        }
        __builtin_amdgcn_s_setprio(0);

        // deferred wei stores: overlap PV tail + next tile's staging
        float* wrow = wei + (long)bh * (TT*(long)TT) + st*128;
#pragma unroll
        for (int m = 0; m < 4; m++)
#pragma unroll
            for (int r = 0; r < 4; r++) {
                int rg = wr*64 + m*16 + l4*4 + r;
#pragma unroll
                for (int n = 0; n < 4; n++) {
                    int col = wc*64 + n*16 + l15;
                    __builtin_nontemporal_store(pv[m][n][r],
                        &wrow[(long)(q0 + rg) * TT + col]);
                }
            }
        BARRIER;           // Ks/Vs/Ps reusable next tile (stores in flight)
    }

    // epilogue: attn [B,T,C] bf16
#pragma unroll
    for (int m = 0; m < 4; m++)
#pragma unroll
        for (int r = 0; r < 4; r++) {
            int rg = wr*64 + m*16 + l4*4 + r;
            long rowbase = ((long)(bh >> 4) * TT + q0 + rg) * CC + (long)(bh & 15) * HSZ;
#pragma unroll
            for (int n = 0; n < 2; n++)
                attn[rowbase + wc*32 + n*16 + l15] = f2b(oacc[m][n][r]);
        }
}

// ---------------- launch -----------------------------------------------------
extern "C" void kernel_launch(void* const* d_in, const int* in_sizes, int n_in,
                              void* d_out, int out_size, void* d_ws, size_t ws_size,
                              hipStream_t stream)
{
    const float* x      = (const float*)d_in[0];
    const float* wq     = (const float*)d_in[1];
    const float* wk     = (const float*)d_in[2];
    const float* wv     = (const float*)d_in[3];
    const float* w_proj = (const float*)d_in[4];
    const float* b_proj = (const float*)d_in[5];
    const float* w1     = (const float*)d_in[6];
    const float* b1     = (const float*)d_in[7];
    const float* w2     = (const float*)d_in[8];
    const float* b2     = (const float*)d_in[9];
    const float* g1     = (const float*)d_in[10];
    const float* be1    = (const float*)d_in[11];
    const float* g2     = (const float*)d_in[12];
    const float* be2    = (const float*)d_in[13];

    float* out_x = (float*)d_out;                  // [B,T,C]
    float* wei   = out_x + (long)NTOK * CC;        // [B,H,T,T] f32

    const long MEL = 1 << 20;
    ushort* ws16 = (ushort*)d_ws;
    ushort* h    = ws16;                 // [4096,1024] bf16 (LN1 out)
    ushort* q_   = ws16 + 4*MEL;         // [B,H,T,HS]   (k_ = q_+4M, vt = q_+8M)
    ushort* k_   = ws16 + 8*MEL;
    ushort* vt   = ws16 + 12*MEL;        // [B,H,HS,T]
    ushort* attn = ws16 + 16*MEL;        // [4096,1024] bf16
    ushort* h2   = ws16 + 20*MEL;        // [4096,1024] bf16 (LN2 out)
    ushort* a1   = ws16 + 24*MEL;        // [4096,4096] bf16
    ushort* wqkvT= ws16 + 40*MEL;        // [3072,1024] bf16 (q rows 0-1023, k, v)
    ushort* w1T  = ws16 + 44*MEL;        // [4096,1024]
    ushort* wpT  = ws16 + 48*MEL;        // [1024,1024]
    ushort* w2T  = ws16 + 49*MEL;        // [1024,4096]
    float*  x1   = (float*)(ws16 + 54*MEL);  // [4096,1024] f32

    // all weight conversions in one launch (12288 x 32x32 tiles)
    cvtall_k<<<12288, 256, 0, stream>>>(wq, wk, wv, w_proj, w1, w2,
                                        wqkvT, wpT, w1T, w2T);

    // 1. h = LN(x)
    ln_k<<<NTOK, 256, 0, stream>>>(x, g1, be1, h);

    // 2. fused q,k,v projection (N=3072; q pre-scaled by QSCALE)
    mgemm_k<128,128,2,2,OL_QKV3,0,ushort><<<dim3(24,32,1), 256, 0, stream>>>(
        h, wqkvT, nullptr, nullptr, q_, NTOK, 3072, CC, 0,0,0, 0.f);

    // 3-5. fused attention: wei (f32, d_out) + attn (bf16 headcat)
    fattn_k<<<dim3(4, 64), 512, 0, stream>>>(q_, k_, vt, wei, attn);

    // 6. x1 = x + attn @ w_proj + b_proj  (f32) — BN=64: 2 blk/CU
    mgemm_k<128,64,2,2,OL_PLAIN,EBIAS|ERES,float><<<dim3(16,32,1), 256, 0, stream>>>(
        attn, wpT, b_proj, x, x1, NTOK, CC, CC, 0,0,0, 0.f);

    // 7. h2 = LN(x1)
    ln_k<<<NTOK, 256, 0, stream>>>(x1, g2, be2, h2);

    // 8. a1 = relu(h2 @ w1 + b1)  bf16
    mgemm_k<128,128,2,2,OL_PLAIN,EBIAS|ERELU,ushort><<<dim3(32,32,1), 256, 0, stream>>>(
        h2, w1T, b1, nullptr, a1, NTOK, DFF, CC, 0,0,0, 0.f);

    // 9. out = x1 + a1 @ w2 + b2  (f32) — BN=64: 2 blk/CU
    mgemm_k<128,64,2,2,OL_PLAIN,EBIAS|ERES,float><<<dim3(16,32,1), 256, 0, stream>>>(
        a1, w2T, b2, x1, out_x, NTOK, CC, DFF, 0,0,0, 0.f);
}

// Round 19
// 341.109 us; speedup vs baseline: 1.0523x; 1.0237x over previous
//
#include <hip/hip_runtime.h>
#include <hip/hip_bf16.h>

// Problem constants
#define BB    4
#define TT    1024
#define CC    1024
#define HH    16
#define HSZ   64
#define DFF   4096
#define NTOK  (BB*TT)          // 4096
#define BHN   (BB*HH)          // 64

typedef __attribute__((ext_vector_type(8))) short bf16x8;
typedef __attribute__((ext_vector_type(4))) float f32x4;

#define VMC0  asm volatile("s_waitcnt vmcnt(0)" ::: "memory")
#define VMC2  asm volatile("s_waitcnt vmcnt(2)" ::: "memory")
#define LGK0  asm volatile("s_waitcnt lgkmcnt(0)" ::: "memory")
#define BARRIER do { asm volatile("" ::: "memory"); \
                     __builtin_amdgcn_s_barrier();  \
                     asm volatile("" ::: "memory"); } while (0)

// 0.125 * log2(e): folded into Q at the QKV epilogue; v_exp_f32 is exp2.
#define QSCALE 0.18033688f

__device__ __forceinline__ ushort f2b(float v) {
    union { float f; unsigned u; } c; c.f = v;
    unsigned r = c.u + 0x7fffu + ((c.u >> 16) & 1u);   // RNE
    return (ushort)(r >> 16);
}
__device__ __forceinline__ void stv(float* p, float v)  { *p = v; }
__device__ __forceinline__ void stv(ushort* p, float v) { *p = f2b(v); }

__device__ __forceinline__ void gload16(const void* g, void* l) {
    __builtin_amdgcn_global_load_lds(
        (const __attribute__((address_space(1))) void*)g,
        (__attribute__((address_space(3))) void*)l, 16, 0, 0);
}

// ---------------- LayerNorm: f32 in -> bf16 out ------------------------------
__global__ __launch_bounds__(256)
void ln_k(const float* __restrict__ x, const float* __restrict__ g,
          const float* __restrict__ be, ushort* __restrict__ o)
{
    __shared__ float s1[4], s2[4];
    long row = blockIdx.x;
    const float4* xr = (const float4*)(x + row * CC);
    float4 v = xr[threadIdx.x];
    float a = v.x + v.y + v.z + v.w;
    float b = v.x*v.x + v.y*v.y + v.z*v.z + v.w*v.w;
    for (int off = 32; off > 0; off >>= 1) {
        a += __shfl_down(a, off);
        b += __shfl_down(b, off);
    }
    if ((threadIdx.x & 63) == 0) { s1[threadIdx.x >> 6] = a; s2[threadIdx.x >> 6] = b; }
    __syncthreads();
    float sum = s1[0] + s1[1] + s1[2] + s1[3];
    float sq  = s2[0] + s2[1] + s2[2] + s2[3];
    float mu  = sum * (1.0f / CC);
    float var = sq * (1.0f / CC) - mu * mu;
    float inv = rsqrtf(var + 1e-5f);
    float4 gg = ((const float4*)g)[threadIdx.x];
    float4 bb = ((const float4*)be)[threadIdx.x];
    ushort4 r;
    r.x = f2b((v.x - mu) * inv * gg.x + bb.x);
    r.y = f2b((v.y - mu) * inv * gg.y + bb.y);
    r.z = f2b((v.z - mu) * inv * gg.z + bb.z);
    r.w = f2b((v.w - mu) * inv * gg.w + bb.w);
    ((ushort4*)(o + row * CC))[threadIdx.x] = r;
}

// ---------------- All weight conversions (transposed f32->bf16), one launch --
__global__ __launch_bounds__(256)
void cvtall_k(const float* __restrict__ wq, const float* __restrict__ wk,
              const float* __restrict__ wv, const float* __restrict__ wproj,
              const float* __restrict__ w1, const float* __restrict__ w2,
              ushort* __restrict__ wqkvT, ushort* __restrict__ wpT,
              ushort* __restrict__ w1T, ushort* __restrict__ w2T)
{
    __shared__ float t[32][33];
    int idx = blockIdx.x;
    const float* src; ushort* dst; int R, Cc, bx, by;
    if (idx < 3072) {                      // wq/wk/wv: 3 x 16 heads x [1024][64]
        int seg = idx >> 10, rem = idx & 1023;
        int z = rem >> 6, tt2 = rem & 63;
        src = (seg == 0 ? wq : seg == 1 ? wk : wv) + (long)z * 65536;
        dst = wqkvT + (long)seg * (1L << 20) + (long)z * 65536;
        R = 1024; Cc = 64; bx = tt2 & 1; by = tt2 >> 1;
    } else if (idx < 4096) {               // w_proj [1024][1024]
        int tt2 = idx - 3072;
        src = wproj; dst = wpT; R = 1024; Cc = 1024; bx = tt2 & 31; by = tt2 >> 5;
    } else if (idx < 8192) {               // w1 [1024][4096]
        int tt2 = idx - 4096;
        src = w1; dst = w1T; R = 1024; Cc = 4096; bx = tt2 & 127; by = tt2 >> 7;
    } else {                               // w2 [4096][1024]
        int tt2 = idx - 8192;
        src = w2; dst = w2T; R = 4096; Cc = 1024; bx = tt2 & 31; by = tt2 >> 5;
    }
    int r0 = by * 32, c0 = bx * 32;
    int tx = threadIdx.x & 31, ty = threadIdx.x >> 5;
#pragma unroll
    for (int i = 0; i < 4; i++)
        t[ty + 8*i][tx] = src[(long)(r0 + ty + 8*i) * Cc + c0 + tx];
    __syncthreads();
#pragma unroll
    for (int i = 0; i < 4; i++)
        dst[(long)(c0 + ty + 8*i) * R + r0 + tx] = f2b(t[tx][ty + 8*i]);
}

// ---------------- bf16 MFMA GEMM (R15 structure: single buffer) --------------
enum { OL_PLAIN = 0, OL_QKV3 = 1 };
constexpr int EBIAS = 1, ERELU = 2, ERES = 4, ESCALE = 8;

template<int BM, int BN, int WM, int WN, int OL, int EPI, typename OutT>
__global__ __launch_bounds__(256)
void mgemm_k(const ushort* __restrict__ A, const ushort* __restrict__ Bt,
             const float* __restrict__ bias, const float* __restrict__ res,
             OutT* __restrict__ C, int M, int N, int K,
             long sA, long sB, long sC, float scale)
{
    constexpr int BK = 64;
    constexpr int FM = BM / WM / 16, FN = BN / WN / 16;
    __shared__ ushort As[BM * BK];
    __shared__ ushort Bs[BN * BK];
    const int tid = threadIdx.x;
    const int w = tid >> 6, l = tid & 63;
    const int wr = w / WN, wc = w % WN;
    const int l15 = l & 15, l4 = l >> 4;
    const int bh = blockIdx.z;
    const ushort* Ap = A  + (long)bh * sA + (long)(blockIdx.y * BM) * K;
    const ushort* Bp = Bt + (long)bh * sB + (long)(blockIdx.x * BN) * K;

    f32x4 acc[FM][FN];
#pragma unroll
    for (int m = 0; m < FM; m++)
#pragma unroll
        for (int n = 0; n < FN; n++) acc[m][n] = (f32x4){0.f, 0.f, 0.f, 0.f};

    const int arow = tid >> 3;
    const int achk = tid & 7;

    for (int k0 = 0; k0 < K; k0 += BK) {
#pragma unroll
        for (int i = 0; i < BM / 32; i++)
            gload16(Ap + (long)(i*32 + arow) * K + k0 + achk*8,
                    &As[(i*32 + w*8) * BK]);
#pragma unroll
        for (int i = 0; i < BN / 32; i++)
            gload16(Bp + (long)(i*32 + arow) * K + k0 + achk*8,
                    &Bs[(i*32 + w*8) * BK]);
        __syncthreads();
#pragma unroll
        for (int kk = 0; kk < 2; kk++) {
            const int ko = kk*32 + l4*8;
            bf16x8 af[FM], bfr[FN];
#pragma unroll
            for (int m = 0; m < FM; m++)
                af[m] = *(const bf16x8*)&As[(wr*(BM/WM) + m*16 + l15) * BK + ko];
#pragma unroll
            for (int n = 0; n < FN; n++)
                bfr[n] = *(const bf16x8*)&Bs[(wc*(BN/WN) + n*16 + l15) * BK + ko];
#pragma unroll
            for (int m = 0; m < FM; m++)
#pragma unroll
                for (int n = 0; n < FN; n++)
                    acc[m][n] = __builtin_amdgcn_mfma_f32_16x16x32_bf16(
                        af[m], bfr[n], acc[m][n], 0, 0, 0);
        }
        __syncthreads();
    }

#pragma unroll
    for (int m = 0; m < FM; m++) {
        int rbase = blockIdx.y*BM + wr*(BM/WM) + m*16 + l4*4;
#pragma unroll
        for (int n = 0; n < FN; n++) {
            int col = blockIdx.x*BN + wc*(BN/WN) + n*16 + l15;
#pragma unroll
            for (int r = 0; r < 4; r++) {
                int row = rbase + r;
                float v = acc[m][n][r];
                if (EPI & ESCALE) v *= scale;
                if (EPI & EBIAS)  v += bias[col];
                if (EPI & ERELU)  v = fmaxf(v, 0.f);
                if (EPI & ERES)   v += res[(long)row * N + col];
                long idx;
                if (OL == OL_PLAIN) {
                    idx = (long)row * N + col;
                } else {
                    // fused QKV: col segment 0=q(pre-scaled),1=k,2=v(transposed)
                    int seg = col >> 10;
                    int cl  = col & 1023;
                    if (seg == 0) v *= QSCALE;
                    long bh_ = ((long)((row >> 10) * HH + (cl >> 6))) * 65536;
                    long off = (seg == 2)
                        ? bh_ + (long)(cl & 63) * 1024 + (row & 1023)
                        : bh_ + (long)(row & 1023) * 64 + (cl & 63);
                    idx = (long)seg * (4L << 20) + off;
                }
                stv(&C[(long)bh * sC + idx], v);
            }
        }
    }
}

// ---------------- Fused attention, QBLK=256, 8 waves, row-per-wave -----------
// Each wave owns 32 FULL rows (all cols) -> Ps is wave-private: the pass-2
// Ps-visibility barrier collapses to lgkmcnt(0) (2 barriers/tile, was 3);
// pass-1 cross-wave sum merge deleted (wave-local butterfly only); Q lives in
// registers (read from global ONCE — not per-tile like the failed R13/R16).
// K/V staging (shared, dbuf, VMC2) identical to the proven R15 scheme.
__global__ __launch_bounds__(512, 2)
void fattn_k(const ushort* __restrict__ q_, const ushort* __restrict__ k_,
             const ushort* __restrict__ vt, float* __restrict__ wei,
             ushort* __restrict__ attn)
{
    __shared__ ushort Ks[128*64];           // 16 KB
    __shared__ ushort Vs[64*128];           // 16 KB (pass1: K dbuf half)
    __shared__ ushort Ps[256*128];          // 64 KB, wave-private 32-row slices

    const int tid = threadIdx.x;
    const int w = tid >> 6, l = tid & 63;   // 8 waves, each owns 32 rows
    const int l15 = l & 15, l4 = l >> 4;
    const int bh = blockIdx.y;
    const int q0 = blockIdx.x * 256;
    const int arow = tid >> 3, achk = tid & 7;   // staging: 64 rows/issue
    const int kchk = achk ^ (arow & 7);          // swizzled source chunk
    const int vrow = tid >> 4;                   // 32 rows/issue, 256B rows
    const int vchk = (tid & 15) ^ (vrow & 15);
    const int sw8  = (l15 & 7) << 3;             // read XOR, 128B rows
    const int sw16 = l15 << 3;                   // read XOR, 256B rows

    const ushort* Qp = q_ + (long)bh * 65536;
    const ushort* Kp = k_ + (long)bh * 65536;
    const ushort* Vp = vt + (long)bh * 65536;

    // stage K tile 0 (2 issues)
#pragma unroll
    for (int i = 0; i < 2; i++)
        gload16(Kp + (long)(i*64 + arow) * 64 + kchk*8, &Ks[(i*64 + w*8)*64]);

    // Q fragments in registers: rows q0 + w*32 + m*16 + l15 (QSCALE applied)
    bf16x8 qf[2][2];
#pragma unroll
    for (int m = 0; m < 2; m++)
#pragma unroll
        for (int kk = 0; kk < 2; kk++)
            qf[m][kk] = *(const bf16x8*)
                &Qp[(long)(q0 + w*32 + m*16 + l15)*64 + kk*32 + l4*8];

    float ssum[2][4];
#pragma unroll
    for (int m = 0; m < 2; m++)
#pragma unroll
        for (int r = 0; r < 4; r++) ssum[m][r] = 0.f;

    // ---- pass 1: row sums of exp2(S); K double-buffered (Ks <-> Vs) ----
    for (int st = 0; st < 8; ++st) {
        const ushort* cur = (st & 1) ? Vs : Ks;
        ushort*       nxt = (st & 1) ? Ks : Vs;
        if (st < 7) {
#pragma unroll
            for (int i = 0; i < 2; i++)
                gload16(Kp + (long)((st+1)*128 + i*64 + arow) * 64 + kchk*8,
                        &nxt[(i*64 + w*8)*64]);
            VMC2;          // current tile's loads done; next-tile 2 in flight
        } else {
            VMC0;
        }
        BARRIER;

        f32x4 sacc[2][8];
#pragma unroll
        for (int m = 0; m < 2; m++)
#pragma unroll
            for (int n = 0; n < 8; n++) sacc[m][n] = (f32x4){0.f,0.f,0.f,0.f};
        __builtin_amdgcn_s_setprio(1);
#pragma unroll
        for (int kk = 0; kk < 2; kk++) {
            const int ko = kk*32 + l4*8;
            bf16x8 bfr[8];
#pragma unroll
            for (int n = 0; n < 8; n++)
                bfr[n] = *(const bf16x8*)&cur[(n*16 + l15)*64 + (ko ^ sw8)];
#pragma unroll
            for (int m = 0; m < 2; m++)
#pragma unroll
                for (int n = 0; n < 8; n++)
                    sacc[m][n] = __builtin_amdgcn_mfma_f32_16x16x32_bf16(
                        qf[m][kk], bfr[n], sacc[m][n], 0, 0, 0);
        }
        __builtin_amdgcn_s_setprio(0);
#pragma unroll
        for (int m = 0; m < 2; m++)
#pragma unroll
            for (int r = 0; r < 4; r++) {
                float s = 0.f;
#pragma unroll
                for (int n = 0; n < 8; n++) s += exp2f(sacc[m][n][r]);
                ssum[m][r] += s;
            }
        BARRIER;           // cur consumed by all waves before restage
    }

    // prefetch pass-2 tile 0 (K0 -> Ks, V0 -> Vs); safe: last barrier passed
#pragma unroll
    for (int i = 0; i < 2; i++)
        gload16(Kp + (long)(i*64 + arow) * 64 + kchk*8, &Ks[(i*64 + w*8)*64]);
#pragma unroll
    for (int i = 0; i < 2; i++)
        gload16(Vp + (long)(i*32 + vrow) * 1024 + vchk*8, &Vs[(i*32 + w*4)*128]);

    // wave-local reduce: 16-lane butterfly -> linv (no cross-wave merge)
    float linv[2][4];
#pragma unroll
    for (int m = 0; m < 2; m++)
#pragma unroll
        for (int r = 0; r < 4; r++) {
            float s = ssum[m][r];
#pragma unroll
            for (int d = 1; d < 16; d <<= 1) s += __shfl_xor(s, d);
            linv[m][r] = 1.0f / s;
        }

    // ---- pass 2: P + PV (2 barriers/tile) ----
    f32x4 oacc[2][4];
#pragma unroll
    for (int m = 0; m < 2; m++)
#pragma unroll
        for (int n = 0; n < 4; n++) oacc[m][n] = (f32x4){0.f,0.f,0.f,0.f};

    for (int st = 0; st < 8; ++st) {
        if (st > 0) {
#pragma unroll
            for (int i = 0; i < 2; i++)
                gload16(Kp + (long)(st*128 + i*64 + arow) * 64 + kchk*8,
                        &Ks[(i*64 + w*8)*64]);
#pragma unroll
            for (int i = 0; i < 2; i++)
                gload16(Vp + (long)(i*32 + vrow) * 1024 + st*128 + vchk*8,
                        &Vs[(i*32 + w*4)*128]);
        }
        VMC0;              // stage done (prev tile's wei stores drained too)
        BARRIER;

        f32x4 sacc[2][8];
#pragma unroll
        for (int m = 0; m < 2; m++)
#pragma unroll
            for (int n = 0; n < 8; n++) sacc[m][n] = (f32x4){0.f,0.f,0.f,0.f};
        __builtin_amdgcn_s_setprio(1);
#pragma unroll
        for (int kk = 0; kk < 2; kk++) {
            const int ko = kk*32 + l4*8;
            bf16x8 bfr[8];
#pragma unroll
            for (int n = 0; n < 8; n++)
                bfr[n] = *(const bf16x8*)&Ks[(n*16 + l15)*64 + (ko ^ sw8)];
#pragma unroll
            for (int m = 0; m < 2; m++)
#pragma unroll
                for (int n = 0; n < 8; n++)
                    sacc[m][n] = __builtin_amdgcn_mfma_f32_16x16x32_bf16(
                        qf[m][kk], bfr[n], sacc[m][n], 0, 0, 0);
        }
        __builtin_amdgcn_s_setprio(0);

        // exp2 + wave-private Ps write; keep normalized p for deferred store
        float pv[2][8][4];
#pragma unroll
        for (int m = 0; m < 2; m++)
#pragma unroll
            for (int r = 0; r < 4; r++) {
                int rg = w*32 + m*16 + l4*4 + r;
                int psw = (rg & 15) << 3;
                float li = linv[m][r];
#pragma unroll
                for (int n = 0; n < 8; n++) {
                    int col = n*16 + l15;
                    float p = exp2f(sacc[m][n][r]) * li;
                    pv[m][n][r] = p;
                    Ps[rg*128 + (col ^ psw)] = f2b(p);
                }
            }
        LGK0;              // within-wave LDS W->R ordering; NO barrier needed

        // PV: O += P @ V (wave-private P rows; shared Vs)
        __builtin_amdgcn_s_setprio(1);
#pragma unroll
        for (int kc = 0; kc < 4; ++kc) {
            const int ko = kc*32 + l4*8;
            bf16x8 pa[2], vb[4];
#pragma unroll
            for (int m = 0; m < 2; m++)
                pa[m] = *(const bf16x8*)&Ps[(w*32 + m*16 + l15)*128 + (ko ^ sw16)];
#pragma unroll
            for (int n = 0; n < 4; n++)
                vb[n] = *(const bf16x8*)&Vs[(n*16 + l15)*128 + (ko ^ sw16)];
#pragma unroll
            for (int m = 0; m < 2; m++)
#pragma unroll
                for (int n = 0; n < 4; n++)
                    oacc[m][n] = __builtin_amdgcn_mfma_f32_16x16x32_bf16(
                        pa[m], vb[n], oacc[m][n], 0, 0, 0);
        }
        __builtin_amdgcn_s_setprio(0);

        // deferred wei stores: overlap next tile's staging
        float* wrow = wei + (long)bh * (TT*(long)TT) + st*128;
#pragma unroll
        for (int m = 0; m < 2; m++)
#pragma unroll
            for (int r = 0; r < 4; r++) {
                int rg = w*32 + m*16 + l4*4 + r;
#pragma unroll
                for (int n = 0; n < 8; n++) {
                    int col = n*16 + l15;
                    __builtin_nontemporal_store(pv[m][n][r],
                        &wrow[(long)(q0 + rg) * TT + col]);
                }
            }
        BARRIER;           // Ks/Vs reusable next tile (stores stay in flight)
    }

    // epilogue: attn [B,T,C] bf16
#pragma unroll
    for (int m = 0; m < 2; m++)
#pragma unroll
        for (int r = 0; r < 4; r++) {
            int rg = w*32 + m*16 + l4*4 + r;
            long rowbase = ((long)(bh >> 4) * TT + q0 + rg) * CC + (long)(bh & 15) * HSZ;
#pragma unroll
            for (int n = 0; n < 4; n++)
                attn[rowbase + n*16 + l15] = f2b(oacc[m][n][r]);
        }
}

// ---------------- launch -----------------------------------------------------
extern "C" void kernel_launch(void* const* d_in, const int* in_sizes, int n_in,
                              void* d_out, int out_size, void* d_ws, size_t ws_size,
                              hipStream_t stream)
{
    const float* x      = (const float*)d_in[0];
    const float* wq     = (const float*)d_in[1];
    const float* wk     = (const float*)d_in[2];
    const float* wv     = (const float*)d_in[3];
    const float* w_proj = (const float*)d_in[4];
    const float* b_proj = (const float*)d_in[5];
    const float* w1     = (const float*)d_in[6];
    const float* b1     = (const float*)d_in[7];
    const float* w2     = (const float*)d_in[8];
    const float* b2     = (const float*)d_in[9];
    const float* g1     = (const float*)d_in[10];
    const float* be1    = (const float*)d_in[11];
    const float* g2     = (const float*)d_in[12];
    const float* be2    = (const float*)d_in[13];

    float* out_x = (float*)d_out;                  // [B,T,C]
    float* wei   = out_x + (long)NTOK * CC;        // [B,H,T,T] f32

    const long MEL = 1 << 20;
    ushort* ws16 = (ushort*)d_ws;
    ushort* h    = ws16;                 // [4096,1024] bf16 (LN1 out)
    ushort* q_   = ws16 + 4*MEL;         // [B,H,T,HS]   (k_ = q_+4M, vt = q_+8M)
    ushort* k_   = ws16 + 8*MEL;
    ushort* vt   = ws16 + 12*MEL;        // [B,H,HS,T]
    ushort* attn = ws16 + 16*MEL;        // [4096,1024] bf16
    ushort* h2   = ws16 + 20*MEL;        // [4096,1024] bf16 (LN2 out)
    ushort* a1   = ws16 + 24*MEL;        // [4096,4096] bf16
    ushort* wqkvT= ws16 + 40*MEL;        // [3072,1024] bf16 (q rows 0-1023, k, v)
    ushort* w1T  = ws16 + 44*MEL;        // [4096,1024]
    ushort* wpT  = ws16 + 48*MEL;        // [1024,1024]
    ushort* w2T  = ws16 + 49*MEL;        // [1024,4096]
    float*  x1   = (float*)(ws16 + 54*MEL);  // [4096,1024] f32

    // all weight conversions in one launch (12288 x 32x32 tiles)
    cvtall_k<<<12288, 256, 0, stream>>>(wq, wk, wv, w_proj, w1, w2,
                                        wqkvT, wpT, w1T, w2T);

    // 1. h = LN(x)
    ln_k<<<NTOK, 256, 0, stream>>>(x, g1, be1, h);

    // 2. fused q,k,v projection (N=3072; q pre-scaled by QSCALE)
    mgemm_k<128,128,2,2,OL_QKV3,0,ushort><<<dim3(24,32,1), 256, 0, stream>>>(
        h, wqkvT, nullptr, nullptr, q_, NTOK, 3072, CC, 0,0,0, 0.f);

    // 3-5. fused attention: wei (f32, d_out) + attn (bf16 headcat)
    fattn_k<<<dim3(4, 64), 512, 0, stream>>>(q_, k_, vt, wei, attn);

    // 6. x1 = x + attn @ w_proj + b_proj  (f32) — BN=64: 2 blk/CU
    mgemm_k<128,64,2,2,OL_PLAIN,EBIAS|ERES,float><<<dim3(16,32,1), 256, 0, stream>>>(
        attn, wpT, b_proj, x, x1, NTOK, CC, CC, 0,0,0, 0.f);

    // 7. h2 = LN(x1)
    ln_k<<<NTOK, 256, 0, stream>>>(x1, g2, be2, h2);

    // 8. a1 = relu(h2 @ w1 + b1)  bf16
    mgemm_k<128,128,2,2,OL_PLAIN,EBIAS|ERELU,ushort><<<dim3(32,32,1), 256, 0, stream>>>(
        h2, w1T, b1, nullptr, a1, NTOK, DFF, CC, 0,0,0, 0.f);

    // 9. out = x1 + a1 @ w2 + b2  (f32) — BN=64: 2 blk/CU
    mgemm_k<128,64,2,2,OL_PLAIN,EBIAS|ERES,float><<<dim3(16,32,1), 256, 0, stream>>>(
        a1, w2T, b2, x1, out_x, NTOK, CC, DFF, 0,0,0, 0.f);
}